// Round 9
// baseline (632.532 us; speedup 1.0000x reference)
//
#include <hip/hip_runtime.h>
#include <math.h>

// ---------------- problem constants ----------------
#define D_MODEL   1024
#define D_INNER   2048
#define D_STATE   64
#define HEADDIM   128
#define NHEADS    16
#define D_CONV    4
#define BATCH     2
#define SEQLEN    4096
#define RMS_EPS   1e-5f
#define D_IN_PROJ 4240

// zxbc buffer (bf16): cols [0,2048)=z, [2048,4096)=x, [4096,4160)=B, [4160,4224)=C
// conv channel for col = col - 2048 (x|B|C concat order matches conv_dim layout).
#define ZX_LD     4224

#define LCHUNK    128
#define NCHUNK    (SEQLEN / LCHUNK)   // 32

typedef __attribute__((ext_vector_type(8))) short short8;
typedef __attribute__((ext_vector_type(4))) float f32x4;

__device__ __forceinline__ ushort f2bf(float f) {
  unsigned u = __float_as_uint(f);
  u += 0x7fff + ((u >> 16) & 1);          // RNE
  return (ushort)(u >> 16);
}
__device__ __forceinline__ float bf2f(ushort h) {
  return __uint_as_float(((unsigned)h) << 16);
}
__device__ __forceinline__ void ld4(const float* p, float* d) {
  float4 v = *(const float4*)p; d[0] = v.x; d[1] = v.y; d[2] = v.z; d[3] = v.w;
}
__device__ __forceinline__ void ld4b(const ushort* p, float* d) {
  ushort4 v = *(const ushort4*)p;
  d[0] = bf2f(v.x); d[1] = bf2f(v.y); d[2] = bf2f(v.z); d[3] = bf2f(v.w);
}

// async global->LDS, 16B per lane (global_load_lds_dwordx4)
__device__ __forceinline__ void gl_lds16(const ushort* g, ushort* l) {
  __builtin_amdgcn_global_load_lds(
      (const __attribute__((address_space(1))) unsigned int*)g,
      (__attribute__((address_space(3))) unsigned int*)l, 16, 0, 0);
}

// ---------------- split fp32 -> bf16 hi/lo planes ----------------
__global__ void cvt_split(const float* __restrict__ w,
                          ushort* __restrict__ hi, ushort* __restrict__ lo, int n4) {
  int i = blockIdx.x * 256 + threadIdx.x;
  if (i >= n4) return;
  float4 v = ((const float4*)w)[i];
  ushort h0 = f2bf(v.x), h1 = f2bf(v.y), h2 = f2bf(v.z), h3 = f2bf(v.w);
  ushort l0 = f2bf(v.x - bf2f(h0)), l1 = f2bf(v.y - bf2f(h1));
  ushort l2 = f2bf(v.z - bf2f(h2)), l3 = f2bf(v.w - bf2f(h3));
  ((ushort4*)hi)[i] = make_ushort4(h0, h1, h2, h3);
  ((ushort4*)lo)[i] = make_ushort4(l0, l1, l2, l3);
}

// ---------------- pure-bf16-plane split NT GEMM: C[M,N] = A[M,K] * B[N,K]^T ------
// ALO=true : 3-term (AhBh + AhBl + AlBh). ALO=false: 2-term (AhBh + AhBl).
// OBF16: store output as bf16 (ldc then counts ushort elements).
template<int BM, bool ALO, bool OBF16>
__launch_bounds__(256, 3)
__global__ void gemm_bf16p(const ushort* __restrict__ Ah, const ushort* __restrict__ Al,
                           const ushort* __restrict__ Bh, const ushort* __restrict__ Bl,
                           float* __restrict__ C, int ldc,
                           int M, int N, int ldab, int Kslice) {
  constexpr int BN = 128, BK = 32;
  constexpr int RT = BM / 32;
  constexpr int CT = 4;

  __shared__ ushort As[ALO ? 2 : 1][BM * BK];
  __shared__ ushort Bs[2][BN * BK];

  const int t    = threadIdx.x;
  const int bm   = blockIdx.y * BM;
  const int bn   = blockIdx.x * BN;
  const int kz   = blockIdx.z;
  const int kb   = kz * Kslice;
  C += (size_t)kz * M * ldc;               // partial plane for split-K
  const int wave = t >> 6, lane = t & 63;
  const int ml   = lane & 15, g4 = lane >> 4;
  const int wr   = wave & 1, wc = wave >> 1;
  const int r0   = wr * RT * 16, c0 = wc * CT * 16;

  f32x4 acc[RT][CT];
#pragma unroll
  for (int i = 0; i < RT; ++i)
#pragma unroll
    for (int j = 0; j < CT; ++j) acc[i][j] = (f32x4){0.f, 0.f, 0.f, 0.f};

  for (int k0 = kb; k0 < kb + Kslice; k0 += BK) {
    __syncthreads();
#pragma unroll
    for (int ii = 0; ii < BM / 64; ++ii) {
      int idx = t + ii * 256;
      int row = idx >> 2, seg = idx & 3;
      size_t go = (size_t)(bm + row) * ldab + k0 + seg * 8;
      gl_lds16(Ah + go, &As[0][idx * 8]);
      if (ALO) gl_lds16(Al + go, &As[ALO ? 1 : 0][idx * 8]);
    }
#pragma unroll
    for (int ii = 0; ii < 2; ++ii) {
      int idx = t + ii * 256;
      int row = idx >> 2, seg = idx & 3;
      size_t go = (size_t)(bn + row) * ldab + k0 + seg * 8;  // rows past N read
      gl_lds16(Bh + go, &Bs[0][idx * 8]);                    // adjacent valid memory
      gl_lds16(Bl + go, &Bs[1][idx * 8]);
    }
    __syncthreads();

    short8 ah[RT], al[RT], bh[CT], bl[CT];
#pragma unroll
    for (int i = 0; i < RT; ++i) {
      int off = (r0 + i * 16 + ml) * BK + g4 * 8;
      ah[i] = *(const short8*)&As[0][off];
      if (ALO) al[i] = *(const short8*)&As[ALO ? 1 : 0][off];
    }
#pragma unroll
    for (int j = 0; j < CT; ++j) {
      int off = (c0 + j * 16 + ml) * BK + g4 * 8;
      bh[j] = *(const short8*)&Bs[0][off];
      bl[j] = *(const short8*)&Bs[1][off];
    }
#pragma unroll
    for (int i = 0; i < RT; ++i)
#pragma unroll
      for (int j = 0; j < CT; ++j) {
        acc[i][j] = __builtin_amdgcn_mfma_f32_16x16x32_bf16(ah[i], bh[j], acc[i][j], 0, 0, 0);
        acc[i][j] = __builtin_amdgcn_mfma_f32_16x16x32_bf16(ah[i], bl[j], acc[i][j], 0, 0, 0);
        if (ALO)
          acc[i][j] = __builtin_amdgcn_mfma_f32_16x16x32_bf16(al[i], bh[j], acc[i][j], 0, 0, 0);
      }
  }

#pragma unroll
  for (int i = 0; i < RT; ++i)
#pragma unroll
    for (int j = 0; j < CT; ++j) {
      int col = bn + c0 + j * 16 + ml;
      if (col < N) {
        int rowb = bm + r0 + i * 16 + g4 * 4;
#pragma unroll
        for (int r = 0; r < 4; ++r) {
          if (OBF16) ((ushort*)C)[(size_t)(rowb + r) * ldc + col] = f2bf(acc[i][j][r]);
          else       C[(size_t)(rowb + r) * ldc + col] = acc[i][j][r];
        }
      }
    }
}

// ---------------- combine split-K partials: out = P0 + P1 ----------------
__global__ void add_out(const float* __restrict__ P, float* __restrict__ out, int n4) {
  int i = blockIdx.x * 256 + threadIdx.x;
  if (i >= n4) return;
  float4 a = ((const float4*)P)[i];
  float4 b = ((const float4*)(P + (size_t)SEQLEN * D_MODEL))[i];
  ((float4*)out)[i] = make_float4(a.x + b.x, a.y + b.y, a.z + b.z, a.w + b.w);
}

// ---------------- combine dt split-K=8 partials ----------------
__global__ void add_dt(const float* __restrict__ P, float* __restrict__ dtb) {
  int i = blockIdx.x * 256 + threadIdx.x;           // over 16384 float4s
  if (i >= SEQLEN * NHEADS / 4) return;
  float4 s = ((const float4*)P)[i];
#pragma unroll
  for (int k = 1; k < 8; ++k) {
    float4 v = ((const float4*)(P + (size_t)k * SEQLEN * NHEADS))[i];
    s.x += v.x; s.y += v.y; s.z += v.z; s.w += v.w;
  }
  ((float4*)dtb)[i] = s;
}

// =================== SSD chunked scan on MFMA ===================
// conv(4)+SiLU fused into LDS staging, reading bf16 zxbc. D*x folded into the
// intra-chunk mask diagonal.

__device__ __forceinline__ void cum_scan(float* cum, float v, int t, float* carry) {
  int lane = t & 63;
#pragma unroll
  for (int off = 1; off < 64; off <<= 1) {
    float o = __shfl_up(v, off);
    if (lane >= off) v += o;
  }
  if (t == 63) *carry = v;
  __syncthreads();
  if (t >= 64 && t < LCHUNK) v += *carry;
  if (t < LCHUNK) cum[t] = v;
  __syncthreads();
}

// conv+silu at (l, zxbc-col): channel = col - 2048; taps read bf16 rows above.
__device__ __forceinline__ void conv4b(const ushort* __restrict__ zx,
                                       const float* __restrict__ cw,
                                       const float* __restrict__ cb,
                                       int l, int col0, float* outv) {
  const ushort* bp = zx + (size_t)l * ZX_LD + col0;
  float r3[4], r2[4], r1[4], r0[4], bb[4];
  ld4b(bp, r3);
  if (l >= 1) ld4b(bp - ZX_LD, r2);     else { r2[0]=r2[1]=r2[2]=r2[3]=0.f; }
  if (l >= 2) ld4b(bp - 2 * ZX_LD, r1); else { r1[0]=r1[1]=r1[2]=r1[3]=0.f; }
  if (l >= 3) ld4b(bp - 3 * ZX_LD, r0); else { r0[0]=r0[1]=r0[2]=r0[3]=0.f; }
  const int ch = col0 - 2048;
  ld4(cb + ch, bb);
#pragma unroll
  for (int j = 0; j < 4; ++j) {
    float w4[4]; ld4(cw + (ch + j) * 4, w4);
    float a = bb[j];
    a = fmaf(w4[0], r0[j], a);
    a = fmaf(w4[1], r1[j], a);
    a = fmaf(w4[2], r2[j], a);
    a = fmaf(w4[3], r3[j], a);
    outv[j] = a / (1.f + __expf(-a));
  }
}

// ---------------- pass A: per-chunk local state via MFMA ----------------
__launch_bounds__(256, 2)
__global__ void passA_ssd(const ushort* __restrict__ zx,
                          const float* __restrict__ dtb,
                          const float* __restrict__ cw, const float* __restrict__ cb,
                          const float* __restrict__ dt_bias,
                          const float* __restrict__ A_log,
                          float* __restrict__ Sc, float* __restrict__ Pc) {
  const int blk = blockIdx.x;
  const int c   = blk & (NCHUNK - 1);
  const int h   = blk >> 5;
  const int l0  = c * LCHUNK;
  const int t   = threadIdx.x;
  const int wave = t >> 6, lane = t & 63;
  const int ml = lane & 15, g4 = lane >> 4;
  const float Ah = -expf(A_log[h]);

  __shared__ float cum[LCHUNK];
  __shared__ float carry;
  __shared__ ushort Xt[2][LCHUNK * 40];   // conv'd X^T slab: [p][s], stride 40
  __shared__ ushort Bt[2][D_STATE * 40];  // (diag(w)·conv'd B)^T slab: [n][s]

  {
    float v = 0.f;
    if (t < LCHUNK) {
      float xv = dtb[(size_t)(l0 + t) * NHEADS + h] + dt_bias[h];
      float sp = (xv > 20.f) ? xv : log1pf(expf(xv));
      v = sp * Ah;
    }
    cum_scan(cum, v, t, &carry);
  }
  const float cend = cum[LCHUNK - 1];

  f32x4 acc[2][4];
#pragma unroll
  for (int i = 0; i < 2; ++i)
#pragma unroll
    for (int j = 0; j < 4; ++j) acc[i][j] = (f32x4){0.f, 0.f, 0.f, 0.f};
  const int p0 = wave * 32;

  for (int slab = 0; slab < 4; ++slab) {
    __syncthreads();
    for (int i = 0; i < 4; ++i) {
      int q = t + i * 256;
      int s = q >> 5, p4 = (q & 31) * 4;
      int l = l0 + slab * 32 + s;
      float xv[4];
      conv4b(zx, cw, cb, l, 2048 + h * HEADDIM + p4, xv);
#pragma unroll
      for (int j = 0; j < 4; ++j) {
        ushort hh = f2bf(xv[j]);
        Xt[0][(p4 + j) * 40 + s] = hh;
        Xt[1][(p4 + j) * 40 + s] = f2bf(xv[j] - bf2f(hh));
      }
    }
    for (int i = 0; i < 2; ++i) {
      int q = t + i * 256;
      int s = q >> 4, n4 = (q & 15) * 4;
      int l = l0 + slab * 32 + s;
      float wd = __expf(cend - cum[slab * 32 + s]);
      float bv[4];
      conv4b(zx, cw, cb, l, 4096 + n4, bv);
#pragma unroll
      for (int j = 0; j < 4; ++j) {
        float val = bv[j] * wd;
        ushort hh = f2bf(val);
        Bt[0][(n4 + j) * 40 + s] = hh;
        Bt[1][(n4 + j) * 40 + s] = f2bf(val - bf2f(hh));
      }
    }
    __syncthreads();

    short8 xa_h[2], xa_l[2];
#pragma unroll
    for (int pi = 0; pi < 2; ++pi) {
      int off = (p0 + pi * 16 + ml) * 40 + g4 * 8;
      xa_h[pi] = *(const short8*)&Xt[0][off];
      xa_l[pi] = *(const short8*)&Xt[1][off];
    }
#pragma unroll
    for (int ni = 0; ni < 4; ++ni) {
      int off = (ni * 16 + ml) * 40 + g4 * 8;
      short8 bh = *(const short8*)&Bt[0][off];
      short8 bl = *(const short8*)&Bt[1][off];
#pragma unroll
      for (int pi = 0; pi < 2; ++pi) {
        acc[pi][ni] = __builtin_amdgcn_mfma_f32_16x16x32_bf16(xa_h[pi], bh, acc[pi][ni], 0, 0, 0);
        acc[pi][ni] = __builtin_amdgcn_mfma_f32_16x16x32_bf16(xa_h[pi], bl, acc[pi][ni], 0, 0, 0);
        acc[pi][ni] = __builtin_amdgcn_mfma_f32_16x16x32_bf16(xa_l[pi], bh, acc[pi][ni], 0, 0, 0);
      }
    }
  }

  float* S = Sc + (size_t)blk * (HEADDIM * D_STATE);
#pragma unroll
  for (int pi = 0; pi < 2; ++pi)
#pragma unroll
    for (int ni = 0; ni < 4; ++ni) {
      int n = ni * 16 + ml;
#pragma unroll
      for (int r = 0; r < 4; ++r) {
        int p = p0 + pi * 16 + g4 * 4 + r;
        S[(size_t)p * D_STATE + n] = acc[pi][ni][r];
      }
    }
  if (t == 0) Pc[blk] = __expf(cend);
}

// ---------------- pass B: exclusive prefix over chunks ----------------
__global__ void scan_passB(float* __restrict__ Sc, const float* __restrict__ Pc) {
  const int h = blockIdx.x;
  const int e = blockIdx.y * 512 + threadIdx.x;
  const size_t hb = (size_t)h * NCHUNK;
  float st = 0.f;
  for (int c = 0; c < NCHUNK; ++c) {
    size_t idx = (hb + c) * (HEADDIM * D_STATE) + e;
    float P = Pc[hb + c];
    float v = Sc[idx];
    Sc[idx] = st;
    st = fmaf(P, st, v);
  }
}

// ---------------- pass C: intra-chunk attention + inter-chunk term -> y ----------
__launch_bounds__(256, 2)
__global__ void passC_ssd(const ushort* __restrict__ zx,
                          const float* __restrict__ dtb,
                          const float* __restrict__ cw, const float* __restrict__ cb,
                          const float* __restrict__ dt_bias,
                          const float* __restrict__ A_log,
                          const float* __restrict__ Dp,
                          const float* __restrict__ Sc,     // exclusive prefix states
                          float* __restrict__ ybuf) {       // [SEQLEN, D_INNER]
  const int blk = blockIdx.x;
  const int c   = blk & (NCHUNK - 1);
  const int h   = blk >> 5;
  const int l0  = c * LCHUNK;
  const int t   = threadIdx.x;
  const int wave = t >> 6, lane = t & 63;
  const int ml = lane & 15, g4 = lane >> 4;
  const float Ah = -expf(A_log[h]);
  const float Dh = Dp[h];

  __shared__ float cum[LCHUNK];
  __shared__ float carry;
  __shared__ ushort Csl[2][2][LCHUNK * 32];
  __shared__ ushort Bsl[2][2][32 * 32];
  __shared__ ushort Msl[2][LCHUNK * 32];
  __shared__ ushort Xt[2][LCHUNK * 40];

  {
    float v = 0.f;
    if (t < LCHUNK) {
      float xv = dtb[(size_t)(l0 + t) * NHEADS + h] + dt_bias[h];
      float sp = (xv > 20.f) ? xv : log1pf(expf(xv));
      v = sp * Ah;
    }
    cum_scan(cum, v, t, &carry);
  }

  // stage C (resident), inline conv: cols 4160..4224
  {
    int row = t >> 1, half = t & 1;
    int l = l0 + row;
    int colbase = 4160 + half * 32;
#pragma unroll
    for (int j0 = 0; j0 < 32; j0 += 4) {
      float cv[4];
      conv4b(zx, cw, cb, l, colbase + j0, cv);
      ushort h0 = f2bf(cv[0]), h1 = f2bf(cv[1]), h2 = f2bf(cv[2]), h3 = f2bf(cv[3]);
      *(ushort4*)&Csl[half][0][row * 32 + j0] = make_ushort4(h0, h1, h2, h3);
      *(ushort4*)&Csl[half][1][row * 32 + j0] =
          make_ushort4(f2bf(cv[0] - bf2f(h0)), f2bf(cv[1] - bf2f(h1)),
                       f2bf(cv[2] - bf2f(h2)), f2bf(cv[3] - bf2f(h3)));
    }
  }

  f32x4 accY[2][8];
#pragma unroll
  for (int i = 0; i < 2; ++i)
#pragma unroll
    for (int j = 0; j < 8; ++j) accY[i][j] = (f32x4){0.f, 0.f, 0.f, 0.f};
  const int t0 = wave * 32;

  // ---- intra-chunk: 4 s-slabs ----
  for (int slab = 0; slab < 4; ++slab) {
    __syncthreads();
    for (int i = 0; i < 2; ++i) {
      int q = t + i * 256;
      int s = q >> 4, c4 = (q & 15) * 4;
      int l = l0 + slab * 32 + s;
      float bv[4];
      conv4b(zx, cw, cb, l, 4096 + c4, bv);
      int ks = c4 >> 5, jj = c4 & 31;
      ushort h0 = f2bf(bv[0]), h1 = f2bf(bv[1]), h2 = f2bf(bv[2]), h3 = f2bf(bv[3]);
      *(ushort4*)&Bsl[ks][0][s * 32 + jj] = make_ushort4(h0, h1, h2, h3);
      *(ushort4*)&Bsl[ks][1][s * 32 + jj] =
          make_ushort4(f2bf(bv[0] - bf2f(h0)), f2bf(bv[1] - bf2f(h1)),
                       f2bf(bv[2] - bf2f(h2)), f2bf(bv[3] - bf2f(h3)));
    }
    for (int i = 0; i < 4; ++i) {
      int q = t + i * 256;
      int s = q >> 5, p4 = (q & 31) * 4;
      int l = l0 + slab * 32 + s;
      float xv[4];
      conv4b(zx, cw, cb, l, 2048 + h * HEADDIM + p4, xv);
#pragma unroll
      for (int j = 0; j < 4; ++j) {
        ushort hh = f2bf(xv[j]);
        Xt[0][(p4 + j) * 40 + s] = hh;
        Xt[1][(p4 + j) * 40 + s] = f2bf(xv[j] - bf2f(hh));
      }
    }
    __syncthreads();

    // phase 1: G = C . B^T for this slab
    f32x4 g[2][2];
#pragma unroll
    for (int i = 0; i < 2; ++i)
#pragma unroll
      for (int j = 0; j < 2; ++j) g[i][j] = (f32x4){0.f, 0.f, 0.f, 0.f};
#pragma unroll
    for (int ks = 0; ks < 2; ++ks) {
      short8 ca_h[2], ca_l[2];
#pragma unroll
      for (int ti = 0; ti < 2; ++ti) {
        int off = (t0 + ti * 16 + ml) * 32 + g4 * 8;
        ca_h[ti] = *(const short8*)&Csl[ks][0][off];
        ca_l[ti] = *(const short8*)&Csl[ks][1][off];
      }
#pragma unroll
      for (int si = 0; si < 2; ++si) {
        int off = (si * 16 + ml) * 32 + g4 * 8;
        short8 bh = *(const short8*)&Bsl[ks][0][off];
        short8 bl = *(const short8*)&Bsl[ks][1][off];
#pragma unroll
        for (int ti = 0; ti < 2; ++ti) {
          g[ti][si] = __builtin_amdgcn_mfma_f32_16x16x32_bf16(ca_h[ti], bh, g[ti][si], 0, 0, 0);
          g[ti][si] = __builtin_amdgcn_mfma_f32_16x16x32_bf16(ca_h[ti], bl, g[ti][si], 0, 0, 0);
          g[ti][si] = __builtin_amdgcn_mfma_f32_16x16x32_bf16(ca_l[ti], bh, g[ti][si], 0, 0, 0);
        }
      }
    }
    // mask + decay (+ D on the diagonal) + split -> Msl
#pragma unroll
    for (int ti = 0; ti < 2; ++ti)
#pragma unroll
      for (int si = 0; si < 2; ++si) {
        int sl = si * 16 + ml;
        int sg = slab * 32 + sl;
#pragma unroll
        for (int r = 0; r < 4; ++r) {
          int tg = t0 + ti * 16 + g4 * 4 + r;
          float coeff = (sg <= tg) ? __expf(cum[tg] - cum[sg]) : 0.f;
          float val = g[ti][si][r] * coeff + ((sg == tg) ? Dh : 0.f);
          ushort hh = f2bf(val);
          Msl[0][tg * 32 + sl] = hh;
          Msl[1][tg * 32 + sl] = f2bf(val - bf2f(hh));
        }
      }
    __syncthreads();
    // phase 2: Y += M . X^T
    {
      short8 ma_h[2], ma_l[2];
#pragma unroll
      for (int ti = 0; ti < 2; ++ti) {
        int off = (t0 + ti * 16 + ml) * 32 + g4 * 8;
        ma_h[ti] = *(const short8*)&Msl[0][off];
        ma_l[ti] = *(const short8*)&Msl[1][off];
      }
#pragma unroll
      for (int pi = 0; pi < 8; ++pi) {
        int off = (pi * 16 + ml) * 40 + g4 * 8;
        short8 xh = *(const short8*)&Xt[0][off];
        short8 xl = *(const short8*)&Xt[1][off];
#pragma unroll
        for (int ti = 0; ti < 2; ++ti) {
          accY[ti][pi] = __builtin_amdgcn_mfma_f32_16x16x32_bf16(ma_h[ti], xh, accY[ti][pi], 0, 0, 0);
          accY[ti][pi] = __builtin_amdgcn_mfma_f32_16x16x32_bf16(ma_h[ti], xl, accY[ti][pi], 0, 0, 0);
          accY[ti][pi] = __builtin_amdgcn_mfma_f32_16x16x32_bf16(ma_l[ti], xh, accY[ti][pi], 0, 0, 0);
        }
      }
    }
  }

  // ---- inter-chunk: Y += diag(exp(cum)) C . S_init ----
  const float* S = Sc + (size_t)blk * (HEADDIM * D_STATE);
  for (int ns = 0; ns < 2; ++ns) {
    __syncthreads();
    for (int i = 0; i < 4; ++i) {
      int q = t + i * 256;
      int p = q >> 3, j4 = (q & 7) * 4;
      float4 v = *(const float4*)(S + (size_t)p * D_STATE + ns * 32 + j4);
      float vv[4] = {v.x, v.y, v.z, v.w};
      ushort hh0 = f2bf(vv[0]), hh1 = f2bf(vv[1]), hh2 = f2bf(vv[2]), hh3 = f2bf(vv[3]);
      *(ushort4*)&Xt[0][p * 40 + j4] = make_ushort4(hh0, hh1, hh2, hh3);
      *(ushort4*)&Xt[1][p * 40 + j4] =
          make_ushort4(f2bf(vv[0] - bf2f(hh0)), f2bf(vv[1] - bf2f(hh1)),
                       f2bf(vv[2] - bf2f(hh2)), f2bf(vv[3] - bf2f(hh3)));
    }
    {
      int row = t >> 1, j0 = (t & 1) * 16;
      float e = __expf(cum[row]);
#pragma unroll
      for (int j = 0; j < 16; ++j) {
        int idx = row * 32 + j0 + j;
        float cv = bf2f(Csl[ns][0][idx]) + bf2f(Csl[ns][1][idx]);
        float val = cv * e;
        ushort hh = f2bf(val);
        Msl[0][idx] = hh;
        Msl[1][idx] = f2bf(val - bf2f(hh));
      }
    }
    __syncthreads();
    {
      short8 ma_h[2], ma_l[2];
#pragma unroll
      for (int ti = 0; ti < 2; ++ti) {
        int off = (t0 + ti * 16 + ml) * 32 + g4 * 8;
        ma_h[ti] = *(const short8*)&Msl[0][off];
        ma_l[ti] = *(const short8*)&Msl[1][off];
      }
#pragma unroll
      for (int pi = 0; pi < 8; ++pi) {
        int off = (pi * 16 + ml) * 40 + g4 * 8;
        short8 xh = *(const short8*)&Xt[0][off];
        short8 xl = *(const short8*)&Xt[1][off];
#pragma unroll
        for (int ti = 0; ti < 2; ++ti) {
          accY[ti][pi] = __builtin_amdgcn_mfma_f32_16x16x32_bf16(ma_h[ti], xh, accY[ti][pi], 0, 0, 0);
          accY[ti][pi] = __builtin_amdgcn_mfma_f32_16x16x32_bf16(ma_h[ti], xl, accY[ti][pi], 0, 0, 0);
          accY[ti][pi] = __builtin_amdgcn_mfma_f32_16x16x32_bf16(ma_l[ti], xh, accY[ti][pi], 0, 0, 0);
        }
      }
    }
  }

  // ---- epilogue: y = accY ----
#pragma unroll
  for (int ti = 0; ti < 2; ++ti)
#pragma unroll
    for (int pi = 0; pi < 8; ++pi) {
      int p = pi * 16 + ml;
#pragma unroll
      for (int r = 0; r < 4; ++r) {
        int l = l0 + t0 + ti * 16 + g4 * 4 + r;
        ybuf[(size_t)l * D_INNER + h * HEADDIM + p] = accY[ti][pi][r];
      }
    }
}

// ------- RMSNorm + sigmoid(z) gate (z bf16 in zxbc), emits gated y bf16 -------
__launch_bounds__(256)
__global__ void rmsnorm_gate_split(const float* __restrict__ ybuf,
                                   const ushort* __restrict__ zx,
                                   const float* __restrict__ rms_w,
                                   ushort* __restrict__ yh) {
  const int row = blockIdx.x;
  const int t   = threadIdx.x;
  const float* y  = ybuf + (size_t)row * D_INNER;
  const ushort* z = zx   + (size_t)row * ZX_LD;      // z cols [0,2048)

  float4 a  = *(const float4*)(y + t * 8);
  float4 bq = *(const float4*)(y + t * 8 + 4);
  float ss = a.x * a.x + a.y * a.y + a.z * a.z + a.w * a.w +
             bq.x * bq.x + bq.y * bq.y + bq.z * bq.z + bq.w * bq.w;
#pragma unroll
  for (int off = 32; off > 0; off >>= 1) ss += __shfl_down(ss, off);
  __shared__ float red[4];
  if ((t & 63) == 0) red[t >> 6] = ss;
  __syncthreads();
  float tot = red[0] + red[1] + red[2] + red[3];
  float scale = rsqrtf(tot * (1.f / (float)D_INNER) + RMS_EPS);

  float vy[8] = {a.x, a.y, a.z, a.w, bq.x, bq.y, bq.z, bq.w};
  ushort4 zv0 = *(const ushort4*)(z + t * 8);
  ushort4 zv1 = *(const ushort4*)(z + t * 8 + 4);
  ushort zz[8] = {zv0.x, zv0.y, zv0.z, zv0.w, zv1.x, zv1.y, zv1.z, zv1.w};
  ushort hh[8];
#pragma unroll
  for (int jj = 0; jj < 8; ++jj) {
    int col = t * 8 + jj;
    float g = 1.f / (1.f + __expf(-bf2f(zz[jj])));
    float v = vy[jj] * scale * rms_w[col] * g;
    hh[jj] = f2bf(v);
  }
  size_t o = (size_t)row * D_INNER + t * 8;
  *(ushort4*)(yh + o)     = make_ushort4(hh[0], hh[1], hh[2], hh[3]);
  *(ushort4*)(yh + o + 4) = make_ushort4(hh[4], hh[5], hh[6], hh[7]);
}

// ---------------- launch ----------------
// ws (floats, 129.8 MB total, < 131 known-good):
//   zxbc bf16 [4096,4224] 8,650,752 | dtb 65,536 | dtp [8,4096,16] 524,288
//   | ybuf [4096,2048] 8,388,608 | Pc 512 | Sc [512,8192] 4,194,304
//   | u planes 4,194,304 | w1 planes 4,341,760 | w2 planes 2,097,152
// Aliases: yh (bf16 y, 16.8MB) overlays Sc after passC; Opart overlays ybuf
//   after rmsnorm.
extern "C" void kernel_launch(void* const* d_in, const int* in_sizes, int n_in,
                              void* d_out, int out_size, void* d_ws, size_t ws_size,
                              hipStream_t stream) {
  const float* u         = (const float*)d_in[0];
  const float* in_proj_w = (const float*)d_in[1];
  const float* conv_w    = (const float*)d_in[2];
  const float* conv_b    = (const float*)d_in[3];
  const float* dt_bias   = (const float*)d_in[4];
  const float* A_log     = (const float*)d_in[5];
  const float* Dp        = (const float*)d_in[6];
  const float* rms_w     = (const float*)d_in[7];
  const float* out_w     = (const float*)d_in[8];
  float* out = (float*)d_out;

  float* ws    = (float*)d_ws;
  ushort* zxbc = (ushort*)ws;                                  // [4096, 4224] bf16
  float* dtb   = ws   + (size_t)SEQLEN * ZX_LD / 2;            // [4096, 16]
  float* dtp   = dtb  + (size_t)SEQLEN * NHEADS;               // [8, 4096, 16]
  float* ybuf  = dtp  + (size_t)8 * SEQLEN * NHEADS;           // [4096, 2048]
  float* Pc    = ybuf + (size_t)SEQLEN * D_INNER;              // [512]
  float* Sc    = Pc   + 512;                                   // [512, 8192]
  ushort* uh   = (ushort*)(Sc + (size_t)NHEADS * NCHUNK * HEADDIM * D_STATE);
  ushort* ul   = uh  + (size_t)SEQLEN * D_MODEL;
  ushort* w1h  = ul  + (size_t)SEQLEN * D_MODEL;
  ushort* w1l  = w1h + (size_t)D_IN_PROJ * D_MODEL;
  ushort* w2h  = w1l + (size_t)D_IN_PROJ * D_MODEL;
  ushort* w2l  = w2h + (size_t)D_MODEL * D_INNER;
  ushort* yh   = (ushort*)Sc;                                  // overlay Sc (dead)
  float* Opart = ybuf;                                         // overlay ybuf (dead)

  // weight splits (once per call)
  {
    int n4 = D_IN_PROJ * D_MODEL / 4;
    cvt_split<<<(n4 + 255) / 256, 256, 0, stream>>>(in_proj_w, w1h, w1l, n4);
    int m4 = D_MODEL * D_INNER / 4;
    cvt_split<<<(m4 + 255) / 256, 256, 0, stream>>>(out_w, w2h, w2l, m4);
  }

  for (int b = 0; b < BATCH; ++b) {
    const float* u_b  = u   + (size_t)b * SEQLEN * D_MODEL;
    float*      out_b = out + (size_t)b * SEQLEN * D_MODEL;

    // 0) split u_b -> bf16 planes
    {
      int n4 = SEQLEN * D_MODEL / 4;
      cvt_split<<<(n4 + 255) / 256, 256, 0, stream>>>(u_b, uh, ul, n4);
    }

    // 1) merged z|x|B|C GEMM (2-term, bf16 out): cols match w1 row order
    {
      dim3 g(ZX_LD / 128, SEQLEN / 128, 1);
      gemm_bf16p<128, false, true><<<g, 256, 0, stream>>>(uh, uh, w1h, w1l,
                                                          (float*)zxbc, ZX_LD, SEQLEN,
                                                          ZX_LD, D_MODEL, D_MODEL);
    }
    // 1b) dt GEMM (3-term, split-K=8): N=16, near-fp32 (dt feeds exponentials)
    {
      const ushort* bh = w1h + (size_t)ZX_LD * D_MODEL;
      const ushort* bl = w1l + (size_t)ZX_LD * D_MODEL;
      dim3 g(1, SEQLEN / 128, 8);
      gemm_bf16p<128, true, false><<<g, 256, 0, stream>>>(uh, ul, bh, bl,
                                                          dtp, NHEADS, SEQLEN, NHEADS,
                                                          D_MODEL, D_MODEL / 8);
      add_dt<<<(SEQLEN * NHEADS / 4 + 255) / 256, 256, 0, stream>>>(dtp, dtb);
    }

    // 2-4) SSD chunked scan on MFMA (conv+SiLU fused; D via mask diagonal)
    passA_ssd<<<NHEADS * NCHUNK, 256, 0, stream>>>(zxbc, dtb, conv_w, conv_b,
                                                   dt_bias, A_log, Sc, Pc);
    scan_passB<<<dim3(NHEADS, (HEADDIM * D_STATE) / 512), 512, 0, stream>>>(Sc, Pc);
    passC_ssd<<<NHEADS * NCHUNK, 256, 0, stream>>>(zxbc, dtb, conv_w, conv_b,
                                                   dt_bias, A_log, Dp, Sc, ybuf);

    // 5) RMSNorm + gate -> y bf16 (overlays Sc, dead now)
    rmsnorm_gate_split<<<SEQLEN, 256, 0, stream>>>(ybuf, zxbc, rms_w, yh);

    // 6) out GEMM, split-K=2, 2-term -> partials over ybuf (dead)
    {
      dim3 g(D_MODEL / 128, SEQLEN / 128, 2);
      gemm_bf16p<128, false, false><<<g, 256, 0, stream>>>(yh, yh, w2h, w2l,
                                                           Opart, D_MODEL, SEQLEN, D_MODEL,
                                                           D_INNER, D_INNER / 2);
    }
    // 7) combine partials -> out_b
    add_out<<<(SEQLEN * D_MODEL / 4 + 255) / 256, 256, 0, stream>>>(Opart, out_b,
                                                                    SEQLEN * D_MODEL / 4);
  }
}

// Round 10
// 592.055 us; speedup vs baseline: 1.0684x; 1.0684x over previous
//
#include <hip/hip_runtime.h>
#include <math.h>

// ---------------- problem constants ----------------
#define D_MODEL   1024
#define D_INNER   2048
#define D_STATE   64
#define HEADDIM   128
#define NHEADS    16
#define D_CONV    4
#define BATCH     2
#define SEQLEN    4096
#define RMS_EPS   1e-5f
#define D_IN_PROJ 4240

// zxbc buffer (bf16): cols [0,2048)=z, [2048,4096)=x, [4096,4160)=B, [4160,4224)=C
#define ZX_LD     4224

#define LCHUNK    128
#define NCHUNK    (SEQLEN / LCHUNK)   // 32

typedef __attribute__((ext_vector_type(8))) short short8;
typedef __attribute__((ext_vector_type(4))) float f32x4;

__device__ __forceinline__ ushort f2bf(float f) {
  unsigned u = __float_as_uint(f);
  u += 0x7fff + ((u >> 16) & 1);          // RNE
  return (ushort)(u >> 16);
}
__device__ __forceinline__ float bf2f(ushort h) {
  return __uint_as_float(((unsigned)h) << 16);
}
__device__ __forceinline__ void ld4(const float* p, float* d) {
  float4 v = *(const float4*)p; d[0] = v.x; d[1] = v.y; d[2] = v.z; d[3] = v.w;
}
__device__ __forceinline__ void ld4b(const ushort* p, float* d) {
  ushort4 v = *(const ushort4*)p;
  d[0] = bf2f(v.x); d[1] = bf2f(v.y); d[2] = bf2f(v.z); d[3] = bf2f(v.w);
}

// async global->LDS, 16B per lane (global_load_lds_dwordx4)
__device__ __forceinline__ void gl_lds16(const ushort* g, ushort* l) {
  __builtin_amdgcn_global_load_lds(
      (const __attribute__((address_space(1))) unsigned int*)g,
      (__attribute__((address_space(3))) unsigned int*)l, 16, 0, 0);
}

// ---------------- split fp32 -> bf16 hi/lo planes ----------------
__global__ void cvt_split(const float* __restrict__ w,
                          ushort* __restrict__ hi, ushort* __restrict__ lo, int n4) {
  int i = blockIdx.x * 256 + threadIdx.x;
  if (i >= n4) return;
  float4 v = ((const float4*)w)[i];
  ushort h0 = f2bf(v.x), h1 = f2bf(v.y), h2 = f2bf(v.z), h3 = f2bf(v.w);
  ushort l0 = f2bf(v.x - bf2f(h0)), l1 = f2bf(v.y - bf2f(h1));
  ushort l2 = f2bf(v.z - bf2f(h2)), l3 = f2bf(v.w - bf2f(h3));
  ((ushort4*)hi)[i] = make_ushort4(h0, h1, h2, h3);
  ((ushort4*)lo)[i] = make_ushort4(l0, l1, l2, l3);
}

// ---------------- pure-bf16-plane split NT GEMM: C[M,N] = A[M,K] * B[N,K]^T ------
// ALO=true : 3-term (AhBh + AhBl + AlBh). ALO=false: 2-term (AhBh + AhBl).
// Columns < n1term use 1-term (AhBh only) — block-uniform branch (z columns).
// OBF16: store output as bf16. Grid.x may be padded past N/BN (early return) so
// that column-tile -> XCD assignment is stable (%8) for L2 residency of B slices.
template<int BM, bool ALO, bool OBF16>
__launch_bounds__(256, 3)
__global__ void gemm_bf16p(const ushort* __restrict__ Ah, const ushort* __restrict__ Al,
                           const ushort* __restrict__ Bh, const ushort* __restrict__ Bl,
                           float* __restrict__ C, int ldc,
                           int M, int N, int ldab, int Kslice, int n1term) {
  constexpr int BN = 128, BK = 32;
  constexpr int RT = BM / 32;
  constexpr int CT = 4;

  __shared__ ushort As[ALO ? 2 : 1][BM * BK];
  __shared__ ushort Bs[2][BN * BK];

  const int bn   = blockIdx.x * BN;
  if (bn >= N) return;                     // padded grid.x tiles exit
  const bool two = (bn >= n1term);         // block-uniform: 2nd B term needed?
  const int t    = threadIdx.x;
  const int bm   = blockIdx.y * BM;
  const int kz   = blockIdx.z;
  const int kb   = kz * Kslice;
  C += (size_t)kz * M * ldc;               // partial plane for split-K
  const int wave = t >> 6, lane = t & 63;
  const int ml   = lane & 15, g4 = lane >> 4;
  const int wr   = wave & 1, wc = wave >> 1;
  const int r0   = wr * RT * 16, c0 = wc * CT * 16;

  f32x4 acc[RT][CT];
#pragma unroll
  for (int i = 0; i < RT; ++i)
#pragma unroll
    for (int j = 0; j < CT; ++j) acc[i][j] = (f32x4){0.f, 0.f, 0.f, 0.f};

  for (int k0 = kb; k0 < kb + Kslice; k0 += BK) {
    __syncthreads();
#pragma unroll
    for (int ii = 0; ii < BM / 64; ++ii) {
      int idx = t + ii * 256;
      int row = idx >> 2, seg = idx & 3;
      size_t go = (size_t)(bm + row) * ldab + k0 + seg * 8;
      gl_lds16(Ah + go, &As[0][idx * 8]);
      if (ALO) gl_lds16(Al + go, &As[ALO ? 1 : 0][idx * 8]);
    }
#pragma unroll
    for (int ii = 0; ii < 2; ++ii) {
      int idx = t + ii * 256;
      int row = idx >> 2, seg = idx & 3;
      size_t go = (size_t)(bn + row) * ldab + k0 + seg * 8;  // rows past N read
      gl_lds16(Bh + go, &Bs[0][idx * 8]);                    // adjacent valid memory
      if (two) gl_lds16(Bl + go, &Bs[1][idx * 8]);
    }
    __syncthreads();

    short8 ah[RT], al[RT], bh[CT], bl[CT];
#pragma unroll
    for (int i = 0; i < RT; ++i) {
      int off = (r0 + i * 16 + ml) * BK + g4 * 8;
      ah[i] = *(const short8*)&As[0][off];
      if (ALO) al[i] = *(const short8*)&As[ALO ? 1 : 0][off];
    }
#pragma unroll
    for (int j = 0; j < CT; ++j) {
      int off = (c0 + j * 16 + ml) * BK + g4 * 8;
      bh[j] = *(const short8*)&Bs[0][off];
      if (two) bl[j] = *(const short8*)&Bs[1][off];
    }
#pragma unroll
    for (int i = 0; i < RT; ++i)
#pragma unroll
      for (int j = 0; j < CT; ++j) {
        acc[i][j] = __builtin_amdgcn_mfma_f32_16x16x32_bf16(ah[i], bh[j], acc[i][j], 0, 0, 0);
        if (two)
          acc[i][j] = __builtin_amdgcn_mfma_f32_16x16x32_bf16(ah[i], bl[j], acc[i][j], 0, 0, 0);
        if (ALO)
          acc[i][j] = __builtin_amdgcn_mfma_f32_16x16x32_bf16(al[i], bh[j], acc[i][j], 0, 0, 0);
      }
  }

#pragma unroll
  for (int i = 0; i < RT; ++i)
#pragma unroll
    for (int j = 0; j < CT; ++j) {
      int col = bn + c0 + j * 16 + ml;
      if (col < N) {
        int rowb = bm + r0 + i * 16 + g4 * 4;
#pragma unroll
        for (int r = 0; r < 4; ++r) {
          if (OBF16) ((ushort*)C)[(size_t)(rowb + r) * ldc + col] = f2bf(acc[i][j][r]);
          else       C[(size_t)(rowb + r) * ldc + col] = acc[i][j][r];
        }
      }
    }
}

// ---------------- combine split-K partials: out = P0 + P1 ----------------
__global__ void add_out(const float* __restrict__ P, float* __restrict__ out, int n4) {
  int i = blockIdx.x * 256 + threadIdx.x;
  if (i >= n4) return;
  float4 a = ((const float4*)P)[i];
  float4 b = ((const float4*)(P + (size_t)SEQLEN * D_MODEL))[i];
  ((float4*)out)[i] = make_float4(a.x + b.x, a.y + b.y, a.z + b.z, a.w + b.w);
}

// ---------------- combine dt split-K=8 partials ----------------
__global__ void add_dt(const float* __restrict__ P, float* __restrict__ dtb) {
  int i = blockIdx.x * 256 + threadIdx.x;           // over 16384 float4s
  if (i >= SEQLEN * NHEADS / 4) return;
  float4 s = ((const float4*)P)[i];
#pragma unroll
  for (int k = 1; k < 8; ++k) {
    float4 v = ((const float4*)(P + (size_t)k * SEQLEN * NHEADS))[i];
    s.x += v.x; s.y += v.y; s.z += v.z; s.w += v.w;
  }
  ((float4*)dtb)[i] = s;
}

// =================== SSD chunked scan on MFMA ===================

__device__ __forceinline__ void cum_scan(float* cum, float v, int t, float* carry) {
  int lane = t & 63;
#pragma unroll
  for (int off = 1; off < 64; off <<= 1) {
    float o = __shfl_up(v, off);
    if (lane >= off) v += o;
  }
  if (t == 63) *carry = v;
  __syncthreads();
  if (t >= 64 && t < LCHUNK) v += *carry;
  if (t < LCHUNK) cum[t] = v;
  __syncthreads();
}

// conv+silu at (l, zxbc-col): channel = col - 2048; taps read bf16 rows above.
__device__ __forceinline__ void conv4b(const ushort* __restrict__ zx,
                                       const float* __restrict__ cw,
                                       const float* __restrict__ cb,
                                       int l, int col0, float* outv) {
  const ushort* bp = zx + (size_t)l * ZX_LD + col0;
  float r3[4], r2[4], r1[4], r0[4], bb[4];
  ld4b(bp, r3);
  if (l >= 1) ld4b(bp - ZX_LD, r2);     else { r2[0]=r2[1]=r2[2]=r2[3]=0.f; }
  if (l >= 2) ld4b(bp - 2 * ZX_LD, r1); else { r1[0]=r1[1]=r1[2]=r1[3]=0.f; }
  if (l >= 3) ld4b(bp - 3 * ZX_LD, r0); else { r0[0]=r0[1]=r0[2]=r0[3]=0.f; }
  const int ch = col0 - 2048;
  ld4(cb + ch, bb);
#pragma unroll
  for (int j = 0; j < 4; ++j) {
    float w4[4]; ld4(cw + (ch + j) * 4, w4);
    float a = bb[j];
    a = fmaf(w4[0], r0[j], a);
    a = fmaf(w4[1], r1[j], a);
    a = fmaf(w4[2], r2[j], a);
    a = fmaf(w4[3], r3[j], a);
    outv[j] = a / (1.f + __expf(-a));
  }
}

// ---------------- pass A: per-chunk local state via MFMA ----------------
__launch_bounds__(256, 2)
__global__ void passA_ssd(const ushort* __restrict__ zx,
                          const float* __restrict__ dtb,
                          const float* __restrict__ cw, const float* __restrict__ cb,
                          const float* __restrict__ dt_bias,
                          const float* __restrict__ A_log,
                          float* __restrict__ Sc, float* __restrict__ Pc) {
  const int blk = blockIdx.x;
  const int c   = blk & (NCHUNK - 1);
  const int h   = blk >> 5;
  const int l0  = c * LCHUNK;
  const int t   = threadIdx.x;
  const int wave = t >> 6, lane = t & 63;
  const int ml = lane & 15, g4 = lane >> 4;
  const float Ah = -expf(A_log[h]);

  __shared__ float cum[LCHUNK];
  __shared__ float carry;
  __shared__ ushort Xt[2][LCHUNK * 40];
  __shared__ ushort Bt[2][D_STATE * 40];

  {
    float v = 0.f;
    if (t < LCHUNK) {
      float xv = dtb[(size_t)(l0 + t) * NHEADS + h] + dt_bias[h];
      float sp = (xv > 20.f) ? xv : log1pf(expf(xv));
      v = sp * Ah;
    }
    cum_scan(cum, v, t, &carry);
  }
  const float cend = cum[LCHUNK - 1];

  f32x4 acc[2][4];
#pragma unroll
  for (int i = 0; i < 2; ++i)
#pragma unroll
    for (int j = 0; j < 4; ++j) acc[i][j] = (f32x4){0.f, 0.f, 0.f, 0.f};
  const int p0 = wave * 32;

  for (int slab = 0; slab < 4; ++slab) {
    __syncthreads();
    for (int i = 0; i < 4; ++i) {
      int q = t + i * 256;
      int s = q >> 5, p4 = (q & 31) * 4;
      int l = l0 + slab * 32 + s;
      float xv[4];
      conv4b(zx, cw, cb, l, 2048 + h * HEADDIM + p4, xv);
#pragma unroll
      for (int j = 0; j < 4; ++j) {
        ushort hh = f2bf(xv[j]);
        Xt[0][(p4 + j) * 40 + s] = hh;
        Xt[1][(p4 + j) * 40 + s] = f2bf(xv[j] - bf2f(hh));
      }
    }
    for (int i = 0; i < 2; ++i) {
      int q = t + i * 256;
      int s = q >> 4, n4 = (q & 15) * 4;
      int l = l0 + slab * 32 + s;
      float wd = __expf(cend - cum[slab * 32 + s]);
      float bv[4];
      conv4b(zx, cw, cb, l, 4096 + n4, bv);
#pragma unroll
      for (int j = 0; j < 4; ++j) {
        float val = bv[j] * wd;
        ushort hh = f2bf(val);
        Bt[0][(n4 + j) * 40 + s] = hh;
        Bt[1][(n4 + j) * 40 + s] = f2bf(val - bf2f(hh));
      }
    }
    __syncthreads();

    short8 xa_h[2], xa_l[2];
#pragma unroll
    for (int pi = 0; pi < 2; ++pi) {
      int off = (p0 + pi * 16 + ml) * 40 + g4 * 8;
      xa_h[pi] = *(const short8*)&Xt[0][off];
      xa_l[pi] = *(const short8*)&Xt[1][off];
    }
#pragma unroll
    for (int ni = 0; ni < 4; ++ni) {
      int off = (ni * 16 + ml) * 40 + g4 * 8;
      short8 bh = *(const short8*)&Bt[0][off];
      short8 bl = *(const short8*)&Bt[1][off];
#pragma unroll
      for (int pi = 0; pi < 2; ++pi) {
        acc[pi][ni] = __builtin_amdgcn_mfma_f32_16x16x32_bf16(xa_h[pi], bh, acc[pi][ni], 0, 0, 0);
        acc[pi][ni] = __builtin_amdgcn_mfma_f32_16x16x32_bf16(xa_h[pi], bl, acc[pi][ni], 0, 0, 0);
        acc[pi][ni] = __builtin_amdgcn_mfma_f32_16x16x32_bf16(xa_l[pi], bh, acc[pi][ni], 0, 0, 0);
      }
    }
  }

  float* S = Sc + (size_t)blk * (HEADDIM * D_STATE);
#pragma unroll
  for (int pi = 0; pi < 2; ++pi)
#pragma unroll
    for (int ni = 0; ni < 4; ++ni) {
      int n = ni * 16 + ml;
#pragma unroll
      for (int r = 0; r < 4; ++r) {
        int p = p0 + pi * 16 + g4 * 4 + r;
        S[(size_t)p * D_STATE + n] = acc[pi][ni][r];
      }
    }
  if (t == 0) Pc[blk] = __expf(cend);
}

// ---------------- pass B: exclusive prefix over chunks ----------------
__global__ void scan_passB(float* __restrict__ Sc, const float* __restrict__ Pc) {
  const int h = blockIdx.x;
  const int e = blockIdx.y * 512 + threadIdx.x;
  const size_t hb = (size_t)h * NCHUNK;
  float st = 0.f;
  for (int c = 0; c < NCHUNK; ++c) {
    size_t idx = (hb + c) * (HEADDIM * D_STATE) + e;
    float P = Pc[hb + c];
    float v = Sc[idx];
    Sc[idx] = st;
    st = fmaf(P, st, v);
  }
}

// ---------------- pass C: intra-chunk attention + inter-chunk term -> y ----------
__launch_bounds__(256, 2)
__global__ void passC_ssd(const ushort* __restrict__ zx,
                          const float* __restrict__ dtb,
                          const float* __restrict__ cw, const float* __restrict__ cb,
                          const float* __restrict__ dt_bias,
                          const float* __restrict__ A_log,
                          const float* __restrict__ Dp,
                          const float* __restrict__ Sc,
                          float* __restrict__ ybuf) {
  const int blk = blockIdx.x;
  const int c   = blk & (NCHUNK - 1);
  const int h   = blk >> 5;
  const int l0  = c * LCHUNK;
  const int t   = threadIdx.x;
  const int wave = t >> 6, lane = t & 63;
  const int ml = lane & 15, g4 = lane >> 4;
  const float Ah = -expf(A_log[h]);
  const float Dh = Dp[h];

  __shared__ float cum[LCHUNK];
  __shared__ float carry;
  __shared__ ushort Csl[2][2][LCHUNK * 32];
  __shared__ ushort Bsl[2][2][32 * 32];
  __shared__ ushort Msl[2][LCHUNK * 32];
  __shared__ ushort Xt[2][LCHUNK * 40];

  {
    float v = 0.f;
    if (t < LCHUNK) {
      float xv = dtb[(size_t)(l0 + t) * NHEADS + h] + dt_bias[h];
      float sp = (xv > 20.f) ? xv : log1pf(expf(xv));
      v = sp * Ah;
    }
    cum_scan(cum, v, t, &carry);
  }

  // stage C (resident), inline conv: cols 4160..4224
  {
    int row = t >> 1, half = t & 1;
    int l = l0 + row;
    int colbase = 4160 + half * 32;
#pragma unroll
    for (int j0 = 0; j0 < 32; j0 += 4) {
      float cv[4];
      conv4b(zx, cw, cb, l, colbase + j0, cv);
      ushort h0 = f2bf(cv[0]), h1 = f2bf(cv[1]), h2 = f2bf(cv[2]), h3 = f2bf(cv[3]);
      *(ushort4*)&Csl[half][0][row * 32 + j0] = make_ushort4(h0, h1, h2, h3);
      *(ushort4*)&Csl[half][1][row * 32 + j0] =
          make_ushort4(f2bf(cv[0] - bf2f(h0)), f2bf(cv[1] - bf2f(h1)),
                       f2bf(cv[2] - bf2f(h2)), f2bf(cv[3] - bf2f(h3)));
    }
  }

  f32x4 accY[2][8];
#pragma unroll
  for (int i = 0; i < 2; ++i)
#pragma unroll
    for (int j = 0; j < 8; ++j) accY[i][j] = (f32x4){0.f, 0.f, 0.f, 0.f};
  const int t0 = wave * 32;

  // ---- intra-chunk: 4 s-slabs ----
  for (int slab = 0; slab < 4; ++slab) {
    __syncthreads();
    for (int i = 0; i < 2; ++i) {
      int q = t + i * 256;
      int s = q >> 4, c4 = (q & 15) * 4;
      int l = l0 + slab * 32 + s;
      float bv[4];
      conv4b(zx, cw, cb, l, 4096 + c4, bv);
      int ks = c4 >> 5, jj = c4 & 31;
      ushort h0 = f2bf(bv[0]), h1 = f2bf(bv[1]), h2 = f2bf(bv[2]), h3 = f2bf(bv[3]);
      *(ushort4*)&Bsl[ks][0][s * 32 + jj] = make_ushort4(h0, h1, h2, h3);
      *(ushort4*)&Bsl[ks][1][s * 32 + jj] =
          make_ushort4(f2bf(bv[0] - bf2f(h0)), f2bf(bv[1] - bf2f(h1)),
                       f2bf(bv[2] - bf2f(h2)), f2bf(bv[3] - bf2f(h3)));
    }
    for (int i = 0; i < 4; ++i) {
      int q = t + i * 256;
      int s = q >> 5, p4 = (q & 31) * 4;
      int l = l0 + slab * 32 + s;
      float xv[4];
      conv4b(zx, cw, cb, l, 2048 + h * HEADDIM + p4, xv);
#pragma unroll
      for (int j = 0; j < 4; ++j) {
        ushort hh = f2bf(xv[j]);
        Xt[0][(p4 + j) * 40 + s] = hh;
        Xt[1][(p4 + j) * 40 + s] = f2bf(xv[j] - bf2f(hh));
      }
    }
    __syncthreads();

    // phase 1: G = C . B^T
    f32x4 g[2][2];
#pragma unroll
    for (int i = 0; i < 2; ++i)
#pragma unroll
      for (int j = 0; j < 2; ++j) g[i][j] = (f32x4){0.f, 0.f, 0.f, 0.f};
#pragma unroll
    for (int ks = 0; ks < 2; ++ks) {
      short8 ca_h[2], ca_l[2];
#pragma unroll
      for (int ti = 0; ti < 2; ++ti) {
        int off = (t0 + ti * 16 + ml) * 32 + g4 * 8;
        ca_h[ti] = *(const short8*)&Csl[ks][0][off];
        ca_l[ti] = *(const short8*)&Csl[ks][1][off];
      }
#pragma unroll
      for (int si = 0; si < 2; ++si) {
        int off = (si * 16 + ml) * 32 + g4 * 8;
        short8 bh = *(const short8*)&Bsl[ks][0][off];
        short8 bl = *(const short8*)&Bsl[ks][1][off];
#pragma unroll
        for (int ti = 0; ti < 2; ++ti) {
          g[ti][si] = __builtin_amdgcn_mfma_f32_16x16x32_bf16(ca_h[ti], bh, g[ti][si], 0, 0, 0);
          g[ti][si] = __builtin_amdgcn_mfma_f32_16x16x32_bf16(ca_h[ti], bl, g[ti][si], 0, 0, 0);
          g[ti][si] = __builtin_amdgcn_mfma_f32_16x16x32_bf16(ca_l[ti], bh, g[ti][si], 0, 0, 0);
        }
      }
    }
    // mask + decay (+ D diagonal) -> Msl
#pragma unroll
    for (int ti = 0; ti < 2; ++ti)
#pragma unroll
      for (int si = 0; si < 2; ++si) {
        int sl = si * 16 + ml;
        int sg = slab * 32 + sl;
#pragma unroll
        for (int r = 0; r < 4; ++r) {
          int tg = t0 + ti * 16 + g4 * 4 + r;
          float coeff = (sg <= tg) ? __expf(cum[tg] - cum[sg]) : 0.f;
          float val = g[ti][si][r] * coeff + ((sg == tg) ? Dh : 0.f);
          ushort hh = f2bf(val);
          Msl[0][tg * 32 + sl] = hh;
          Msl[1][tg * 32 + sl] = f2bf(val - bf2f(hh));
        }
      }
    __syncthreads();
    // phase 2: Y += M . X^T
    {
      short8 ma_h[2], ma_l[2];
#pragma unroll
      for (int ti = 0; ti < 2; ++ti) {
        int off = (t0 + ti * 16 + ml) * 32 + g4 * 8;
        ma_h[ti] = *(const short8*)&Msl[0][off];
        ma_l[ti] = *(const short8*)&Msl[1][off];
      }
#pragma unroll
      for (int pi = 0; pi < 8; ++pi) {
        int off = (pi * 16 + ml) * 40 + g4 * 8;
        short8 xh = *(const short8*)&Xt[0][off];
        short8 xl = *(const short8*)&Xt[1][off];
#pragma unroll
        for (int ti = 0; ti < 2; ++ti) {
          accY[ti][pi] = __builtin_amdgcn_mfma_f32_16x16x32_bf16(ma_h[ti], xh, accY[ti][pi], 0, 0, 0);
          accY[ti][pi] = __builtin_amdgcn_mfma_f32_16x16x32_bf16(ma_h[ti], xl, accY[ti][pi], 0, 0, 0);
          accY[ti][pi] = __builtin_amdgcn_mfma_f32_16x16x32_bf16(ma_l[ti], xh, accY[ti][pi], 0, 0, 0);
        }
      }
    }
  }

  // ---- inter-chunk: Y += diag(exp(cum)) C . S_init ----
  const float* S = Sc + (size_t)blk * (HEADDIM * D_STATE);
  for (int ns = 0; ns < 2; ++ns) {
    __syncthreads();
    for (int i = 0; i < 4; ++i) {
      int q = t + i * 256;
      int p = q >> 3, j4 = (q & 7) * 4;
      float4 v = *(const float4*)(S + (size_t)p * D_STATE + ns * 32 + j4);
      float vv[4] = {v.x, v.y, v.z, v.w};
      ushort hh0 = f2bf(vv[0]), hh1 = f2bf(vv[1]), hh2 = f2bf(vv[2]), hh3 = f2bf(vv[3]);
      *(ushort4*)&Xt[0][p * 40 + j4] = make_ushort4(hh0, hh1, hh2, hh3);
      *(ushort4*)&Xt[1][p * 40 + j4] =
          make_ushort4(f2bf(vv[0] - bf2f(hh0)), f2bf(vv[1] - bf2f(hh1)),
                       f2bf(vv[2] - bf2f(hh2)), f2bf(vv[3] - bf2f(hh3)));
    }
    {
      int row = t >> 1, j0 = (t & 1) * 16;
      float e = __expf(cum[row]);
#pragma unroll
      for (int j = 0; j < 16; ++j) {
        int idx = row * 32 + j0 + j;
        float cv = bf2f(Csl[ns][0][idx]) + bf2f(Csl[ns][1][idx]);
        float val = cv * e;
        ushort hh = f2bf(val);
        Msl[0][idx] = hh;
        Msl[1][idx] = f2bf(val - bf2f(hh));
      }
    }
    __syncthreads();
    {
      short8 ma_h[2], ma_l[2];
#pragma unroll
      for (int ti = 0; ti < 2; ++ti) {
        int off = (t0 + ti * 16 + ml) * 32 + g4 * 8;
        ma_h[ti] = *(const short8*)&Msl[0][off];
        ma_l[ti] = *(const short8*)&Msl[1][off];
      }
#pragma unroll
      for (int pi = 0; pi < 8; ++pi) {
        int off = (pi * 16 + ml) * 40 + g4 * 8;
        short8 xh = *(const short8*)&Xt[0][off];
        short8 xl = *(const short8*)&Xt[1][off];
#pragma unroll
        for (int ti = 0; ti < 2; ++ti) {
          accY[ti][pi] = __builtin_amdgcn_mfma_f32_16x16x32_bf16(ma_h[ti], xh, accY[ti][pi], 0, 0, 0);
          accY[ti][pi] = __builtin_amdgcn_mfma_f32_16x16x32_bf16(ma_h[ti], xl, accY[ti][pi], 0, 0, 0);
          accY[ti][pi] = __builtin_amdgcn_mfma_f32_16x16x32_bf16(ma_l[ti], xh, accY[ti][pi], 0, 0, 0);
        }
      }
    }
  }

  // ---- epilogue: y = accY ----
#pragma unroll
  for (int ti = 0; ti < 2; ++ti)
#pragma unroll
    for (int pi = 0; pi < 8; ++pi) {
      int p = pi * 16 + ml;
#pragma unroll
      for (int r = 0; r < 4; ++r) {
        int l = l0 + t0 + ti * 16 + g4 * 4 + r;
        ybuf[(size_t)l * D_INNER + h * HEADDIM + p] = accY[ti][pi][r];
      }
    }
}

// ------- RMSNorm + sigmoid(z) gate (z bf16 in zxbc), emits gated y bf16 -------
__launch_bounds__(256)
__global__ void rmsnorm_gate_split(const float* __restrict__ ybuf,
                                   const ushort* __restrict__ zx,
                                   const float* __restrict__ rms_w,
                                   ushort* __restrict__ yh) {
  const int row = blockIdx.x;
  const int t   = threadIdx.x;
  const float* y  = ybuf + (size_t)row * D_INNER;
  const ushort* z = zx   + (size_t)row * ZX_LD;      // z cols [0,2048)

  float4 a  = *(const float4*)(y + t * 8);
  float4 bq = *(const float4*)(y + t * 8 + 4);
  float ss = a.x * a.x + a.y * a.y + a.z * a.z + a.w * a.w +
             bq.x * bq.x + bq.y * bq.y + bq.z * bq.z + bq.w * bq.w;
#pragma unroll
  for (int off = 32; off > 0; off >>= 1) ss += __shfl_down(ss, off);
  __shared__ float red[4];
  if ((t & 63) == 0) red[t >> 6] = ss;
  __syncthreads();
  float tot = red[0] + red[1] + red[2] + red[3];
  float scale = rsqrtf(tot * (1.f / (float)D_INNER) + RMS_EPS);

  float vy[8] = {a.x, a.y, a.z, a.w, bq.x, bq.y, bq.z, bq.w};
  ushort4 zv0 = *(const ushort4*)(z + t * 8);
  ushort4 zv1 = *(const ushort4*)(z + t * 8 + 4);
  ushort zz[8] = {zv0.x, zv0.y, zv0.z, zv0.w, zv1.x, zv1.y, zv1.z, zv1.w};
  ushort hh[8];
#pragma unroll
  for (int jj = 0; jj < 8; ++jj) {
    int col = t * 8 + jj;
    float g = 1.f / (1.f + __expf(-bf2f(zz[jj])));
    float v = vy[jj] * scale * rms_w[col] * g;
    hh[jj] = f2bf(v);
  }
  size_t o = (size_t)row * D_INNER + t * 8;
  *(ushort4*)(yh + o)     = make_ushort4(hh[0], hh[1], hh[2], hh[3]);
  *(ushort4*)(yh + o + 4) = make_ushort4(hh[4], hh[5], hh[6], hh[7]);
}

// ---------------- launch ----------------
// ws layout identical to R9 (129.8 MB, known-good).
extern "C" void kernel_launch(void* const* d_in, const int* in_sizes, int n_in,
                              void* d_out, int out_size, void* d_ws, size_t ws_size,
                              hipStream_t stream) {
  const float* u         = (const float*)d_in[0];
  const float* in_proj_w = (const float*)d_in[1];
  const float* conv_w    = (const float*)d_in[2];
  const float* conv_b    = (const float*)d_in[3];
  const float* dt_bias   = (const float*)d_in[4];
  const float* A_log     = (const float*)d_in[5];
  const float* Dp        = (const float*)d_in[6];
  const float* rms_w     = (const float*)d_in[7];
  const float* out_w     = (const float*)d_in[8];
  float* out = (float*)d_out;

  float* ws    = (float*)d_ws;
  ushort* zxbc = (ushort*)ws;                                  // [4096, 4224] bf16
  float* dtb   = ws   + (size_t)SEQLEN * ZX_LD / 2;            // [4096, 16]
  float* dtp   = dtb  + (size_t)SEQLEN * NHEADS;               // [8, 4096, 16]
  float* ybuf  = dtp  + (size_t)8 * SEQLEN * NHEADS;           // [4096, 2048]
  float* Pc    = ybuf + (size_t)SEQLEN * D_INNER;              // [512]
  float* Sc    = Pc   + 512;                                   // [512, 8192]
  ushort* uh   = (ushort*)(Sc + (size_t)NHEADS * NCHUNK * HEADDIM * D_STATE);
  ushort* ul   = uh  + (size_t)SEQLEN * D_MODEL;
  ushort* w1h  = ul  + (size_t)SEQLEN * D_MODEL;
  ushort* w1l  = w1h + (size_t)D_IN_PROJ * D_MODEL;
  ushort* w2h  = w1l + (size_t)D_IN_PROJ * D_MODEL;
  ushort* w2l  = w2h + (size_t)D_MODEL * D_INNER;
  ushort* yh   = (ushort*)Sc;                                  // overlay Sc (dead)
  float* Opart = ybuf;                                         // overlay ybuf (dead)

  // weight splits (once per call)
  {
    int n4 = D_IN_PROJ * D_MODEL / 4;
    cvt_split<<<(n4 + 255) / 256, 256, 0, stream>>>(in_proj_w, w1h, w1l, n4);
    int m4 = D_MODEL * D_INNER / 4;
    cvt_split<<<(m4 + 255) / 256, 256, 0, stream>>>(out_w, w2h, w2l, m4);
  }

  for (int b = 0; b < BATCH; ++b) {
    const float* u_b  = u   + (size_t)b * SEQLEN * D_MODEL;
    float*      out_b = out + (size_t)b * SEQLEN * D_MODEL;

    // 0) split u_b -> bf16 planes
    {
      int n4 = SEQLEN * D_MODEL / 4;
      cvt_split<<<(n4 + 255) / 256, 256, 0, stream>>>(u_b, uh, ul, n4);
    }

    // 1) merged z|x|B|C GEMM: z cols (<2048) 1-term, x|B|C 2-term, bf16 out.
    //    grid.x padded 33->40 so col-tile -> XCD (%8) is stable: each XCD's B
    //    slice (~2.5MB) stays L2-resident across all 32 row tiles.
    {
      dim3 g(40, SEQLEN / 128, 1);
      gemm_bf16p<128, false, true><<<g, 256, 0, stream>>>(uh, uh, w1h, w1l,
                                                          (float*)zxbc, ZX_LD, SEQLEN,
                                                          ZX_LD, D_MODEL, D_MODEL,
                                                          D_INNER);
    }
    // 1b) dt GEMM (3-term, split-K=8): N=16, near-fp32 (dt feeds exponentials)
    {
      const ushort* bh = w1h + (size_t)ZX_LD * D_MODEL;
      const ushort* bl = w1l + (size_t)ZX_LD * D_MODEL;
      dim3 g(1, SEQLEN / 128, 8);
      gemm_bf16p<128, true, false><<<g, 256, 0, stream>>>(uh, ul, bh, bl,
                                                          dtp, NHEADS, SEQLEN, NHEADS,
                                                          D_MODEL, D_MODEL / 8, 0);
      add_dt<<<(SEQLEN * NHEADS / 4 + 255) / 256, 256, 0, stream>>>(dtp, dtb);
    }

    // 2-4) SSD chunked scan on MFMA (conv+SiLU fused; D via mask diagonal)
    passA_ssd<<<NHEADS * NCHUNK, 256, 0, stream>>>(zxbc, dtb, conv_w, conv_b,
                                                   dt_bias, A_log, Sc, Pc);
    scan_passB<<<dim3(NHEADS, (HEADDIM * D_STATE) / 512), 512, 0, stream>>>(Sc, Pc);
    passC_ssd<<<NHEADS * NCHUNK, 256, 0, stream>>>(zxbc, dtb, conv_w, conv_b,
                                                   dt_bias, A_log, Dp, Sc, ybuf);

    // 5) RMSNorm + gate -> y bf16 (overlays Sc, dead now)
    rmsnorm_gate_split<<<SEQLEN, 256, 0, stream>>>(ybuf, zxbc, rms_w, yh);

    // 6) out GEMM, split-K=2, 2-term -> partials over ybuf (dead)
    {
      dim3 g(D_MODEL / 128, SEQLEN / 128, 2);
      gemm_bf16p<128, false, false><<<g, 256, 0, stream>>>(yh, yh, w2h, w2l,
                                                           Opart, D_MODEL, SEQLEN, D_MODEL,
                                                           D_INNER, D_INNER / 2, 0);
    }
    // 7) combine partials -> out_b
    add_out<<<(SEQLEN * D_MODEL / 4 + 255) / 256, 256, 0, stream>>>(Opart, out_b,
                                                                    SEQLEN * D_MODEL / 4);
  }
}

// Round 11
// 563.517 us; speedup vs baseline: 1.1225x; 1.0506x over previous
//
#include <hip/hip_runtime.h>
#include <math.h>

// ---------------- problem constants ----------------
#define D_MODEL   1024
#define D_INNER   2048
#define D_STATE   64
#define HEADDIM   128
#define NHEADS    16
#define D_CONV    4
#define BATCH     2
#define SEQLEN    4096
#define RMS_EPS   1e-5f
#define D_IN_PROJ 4240

// zxbc buffer (bf16): cols [0,2048)=z, [2048,4096)=x, [4096,4160)=B, [4160,4224)=C
#define ZX_LD     4224

#define LCHUNK    128
#define NCHUNK    (SEQLEN / LCHUNK)   // 32

typedef __attribute__((ext_vector_type(8))) short short8;
typedef __attribute__((ext_vector_type(4))) float f32x4;

__device__ __forceinline__ ushort f2bf(float f) {
  unsigned u = __float_as_uint(f);
  u += 0x7fff + ((u >> 16) & 1);          // RNE
  return (ushort)(u >> 16);
}
__device__ __forceinline__ float bf2f(ushort h) {
  return __uint_as_float(((unsigned)h) << 16);
}
__device__ __forceinline__ void ld4(const float* p, float* d) {
  float4 v = *(const float4*)p; d[0] = v.x; d[1] = v.y; d[2] = v.z; d[3] = v.w;
}
__device__ __forceinline__ void ld4b(const ushort* p, float* d) {
  ushort4 v = *(const ushort4*)p;
  d[0] = bf2f(v.x); d[1] = bf2f(v.y); d[2] = bf2f(v.z); d[3] = bf2f(v.w);
}

// async global->LDS, 16B per lane (global_load_lds_dwordx4)
__device__ __forceinline__ void gl_lds16(const ushort* g, ushort* l) {
  __builtin_amdgcn_global_load_lds(
      (const __attribute__((address_space(1))) unsigned int*)g,
      (__attribute__((address_space(3))) unsigned int*)l, 16, 0, 0);
}

// ---------------- split fp32 -> bf16 hi/lo planes ----------------
__global__ void cvt_split(const float* __restrict__ w,
                          ushort* __restrict__ hi, ushort* __restrict__ lo, int n4) {
  int i = blockIdx.x * 256 + threadIdx.x;
  if (i >= n4) return;
  float4 v = ((const float4*)w)[i];
  ushort h0 = f2bf(v.x), h1 = f2bf(v.y), h2 = f2bf(v.z), h3 = f2bf(v.w);
  ushort l0 = f2bf(v.x - bf2f(h0)), l1 = f2bf(v.y - bf2f(h1));
  ushort l2 = f2bf(v.z - bf2f(h2)), l3 = f2bf(v.w - bf2f(h3));
  ((ushort4*)hi)[i] = make_ushort4(h0, h1, h2, h3);
  ((ushort4*)lo)[i] = make_ushort4(l0, l1, l2, l3);
}

// ---------------- pure-bf16-plane split NT GEMM: C[M,N] = A[M,K] * B[N,K]^T ------
// ALO=true : 3-term (AhBh + AhBl + AlBh). ALO=false: 2-term (AhBh + AhBl).
// Columns < n1term use 1-term (AhBh only) — block-uniform branch (z columns).
// OBF16: store output as bf16. Grid.x may be padded past N/BN (early return) for
// stable col-tile -> XCD (%8) mapping (L2 residency of B slices).
// XOR-swizzled staging: gl_lds16 forces LDS slot = lane order, so the GLOBAL quad
// fetched into slot (row,qs) is qg = qs ^ (row & (NQ-1)); fragment reads un-swizzle.
// This spreads the b128 fragment reads across all 32 banks (2-way = free).
template<int BM, int BK, bool ALO, bool OBF16>
__launch_bounds__(256, 3)
__global__ void gemm_bf16p(const ushort* __restrict__ Ah, const ushort* __restrict__ Al,
                           const ushort* __restrict__ Bh, const ushort* __restrict__ Bl,
                           float* __restrict__ C, int ldc,
                           int M, int N, int ldab, int Kslice, int n1term) {
  constexpr int BN = 128;
  constexpr int NQ = BK / 8;               // quads (8 ushorts) per row
  constexpr int RT = BM / 32;
  constexpr int CT = 4;
  constexpr int KS = BK / 32;              // 32-wide k-steps per K-iter

  __shared__ ushort As[ALO ? 2 : 1][BM * BK];
  __shared__ ushort Bs[2][BN * BK];

  const int bn   = blockIdx.x * BN;
  if (bn >= N) return;                     // padded grid.x tiles exit
  const bool two = (bn >= n1term);         // block-uniform: 2nd B term needed?
  const int t    = threadIdx.x;
  const int bm   = blockIdx.y * BM;
  const int kz   = blockIdx.z;
  const int kb   = kz * Kslice;
  C += (size_t)kz * M * ldc;               // partial plane for split-K
  const int wave = t >> 6, lane = t & 63;
  const int ml   = lane & 15, g4 = lane >> 4;
  const int sw   = ml & (NQ - 1);          // fragment un-swizzle (row&(NQ-1)==ml&..)
  const int wr   = wave & 1, wc = wave >> 1;
  const int r0   = wr * RT * 16, c0 = wc * CT * 16;

  f32x4 acc[RT][CT];
#pragma unroll
  for (int i = 0; i < RT; ++i)
#pragma unroll
    for (int j = 0; j < CT; ++j) acc[i][j] = (f32x4){0.f, 0.f, 0.f, 0.f};

  for (int k0 = kb; k0 < kb + Kslice; k0 += BK) {
    __syncthreads();
    // ---- staging (swizzled) ----
#pragma unroll
    for (int ii = 0; ii < BM * NQ / 256; ++ii) {
      int idx = t + ii * 256;
      int row = idx / NQ, qs = idx % NQ;
      int qg  = qs ^ (row & (NQ - 1));
      size_t go = (size_t)(bm + row) * ldab + k0 + qg * 8;
      gl_lds16(Ah + go, &As[0][idx * 8]);
      if (ALO) gl_lds16(Al + go, &As[ALO ? 1 : 0][idx * 8]);
    }
#pragma unroll
    for (int ii = 0; ii < BN * NQ / 256; ++ii) {
      int idx = t + ii * 256;
      int row = idx / NQ, qs = idx % NQ;
      int qg  = qs ^ (row & (NQ - 1));
      size_t go = (size_t)(bn + row) * ldab + k0 + qg * 8;   // rows past N read
      gl_lds16(Bh + go, &Bs[0][idx * 8]);                    // adjacent valid memory
      if (two) gl_lds16(Bl + go, &Bs[1][idx * 8]);
    }
    __syncthreads();

    // ---- fragments + MFMA, per 32-wide k-step ----
#pragma unroll
    for (int ks = 0; ks < KS; ++ks) {
      const int qA = ((ks * 4 + g4) ^ sw) * 8;
      short8 ah[RT], al[RT], bh[CT], bl[CT];
#pragma unroll
      for (int i = 0; i < RT; ++i) {
        int off = (r0 + i * 16 + ml) * BK + qA;
        ah[i] = *(const short8*)&As[0][off];
        if (ALO) al[i] = *(const short8*)&As[ALO ? 1 : 0][off];
      }
#pragma unroll
      for (int j = 0; j < CT; ++j) {
        int off = (c0 + j * 16 + ml) * BK + qA;
        bh[j] = *(const short8*)&Bs[0][off];
        if (two) bl[j] = *(const short8*)&Bs[1][off];
      }
#pragma unroll
      for (int i = 0; i < RT; ++i)
#pragma unroll
        for (int j = 0; j < CT; ++j) {
          acc[i][j] = __builtin_amdgcn_mfma_f32_16x16x32_bf16(ah[i], bh[j], acc[i][j], 0, 0, 0);
          if (two)
            acc[i][j] = __builtin_amdgcn_mfma_f32_16x16x32_bf16(ah[i], bl[j], acc[i][j], 0, 0, 0);
          if (ALO)
            acc[i][j] = __builtin_amdgcn_mfma_f32_16x16x32_bf16(al[i], bh[j], acc[i][j], 0, 0, 0);
        }
    }
  }

#pragma unroll
  for (int i = 0; i < RT; ++i)
#pragma unroll
    for (int j = 0; j < CT; ++j) {
      int col = bn + c0 + j * 16 + ml;
      if (col < N) {
        int rowb = bm + r0 + i * 16 + g4 * 4;
#pragma unroll
        for (int r = 0; r < 4; ++r) {
          if (OBF16) ((ushort*)C)[(size_t)(rowb + r) * ldc + col] = f2bf(acc[i][j][r]);
          else       C[(size_t)(rowb + r) * ldc + col] = acc[i][j][r];
        }
      }
    }
}

// ---------------- combine split-K partials: out = P0 + P1 ----------------
__global__ void add_out(const float* __restrict__ P, float* __restrict__ out, int n4) {
  int i = blockIdx.x * 256 + threadIdx.x;
  if (i >= n4) return;
  float4 a = ((const float4*)P)[i];
  float4 b = ((const float4*)(P + (size_t)SEQLEN * D_MODEL))[i];
  ((float4*)out)[i] = make_float4(a.x + b.x, a.y + b.y, a.z + b.z, a.w + b.w);
}

// ---------------- combine dt split-K=8 partials ----------------
__global__ void add_dt(const float* __restrict__ P, float* __restrict__ dtb) {
  int i = blockIdx.x * 256 + threadIdx.x;           // over 16384 float4s
  if (i >= SEQLEN * NHEADS / 4) return;
  float4 s = ((const float4*)P)[i];
#pragma unroll
  for (int k = 1; k < 8; ++k) {
    float4 v = ((const float4*)(P + (size_t)k * SEQLEN * NHEADS))[i];
    s.x += v.x; s.y += v.y; s.z += v.z; s.w += v.w;
  }
  ((float4*)dtb)[i] = s;
}

// =================== SSD chunked scan on MFMA ===================

__device__ __forceinline__ void cum_scan(float* cum, float v, int t, float* carry) {
  int lane = t & 63;
#pragma unroll
  for (int off = 1; off < 64; off <<= 1) {
    float o = __shfl_up(v, off);
    if (lane >= off) v += o;
  }
  if (t == 63) *carry = v;
  __syncthreads();
  if (t >= 64 && t < LCHUNK) v += *carry;
  if (t < LCHUNK) cum[t] = v;
  __syncthreads();
}

// conv+silu at (l, zxbc-col): channel = col - 2048; taps read bf16 rows above.
__device__ __forceinline__ void conv4b(const ushort* __restrict__ zx,
                                       const float* __restrict__ cw,
                                       const float* __restrict__ cb,
                                       int l, int col0, float* outv) {
  const ushort* bp = zx + (size_t)l * ZX_LD + col0;
  float r3[4], r2[4], r1[4], r0[4], bb[4];
  ld4b(bp, r3);
  if (l >= 1) ld4b(bp - ZX_LD, r2);     else { r2[0]=r2[1]=r2[2]=r2[3]=0.f; }
  if (l >= 2) ld4b(bp - 2 * ZX_LD, r1); else { r1[0]=r1[1]=r1[2]=r1[3]=0.f; }
  if (l >= 3) ld4b(bp - 3 * ZX_LD, r0); else { r0[0]=r0[1]=r0[2]=r0[3]=0.f; }
  const int ch = col0 - 2048;
  ld4(cb + ch, bb);
#pragma unroll
  for (int j = 0; j < 4; ++j) {
    float w4[4]; ld4(cw + (ch + j) * 4, w4);
    float a = bb[j];
    a = fmaf(w4[0], r0[j], a);
    a = fmaf(w4[1], r1[j], a);
    a = fmaf(w4[2], r2[j], a);
    a = fmaf(w4[3], r3[j], a);
    outv[j] = a / (1.f + __expf(-a));
  }
}

// ---------------- pass A: per-chunk local state via MFMA ----------------
__launch_bounds__(256, 2)
__global__ void passA_ssd(const ushort* __restrict__ zx,
                          const float* __restrict__ dtb,
                          const float* __restrict__ cw, const float* __restrict__ cb,
                          const float* __restrict__ dt_bias,
                          const float* __restrict__ A_log,
                          float* __restrict__ Sc, float* __restrict__ Pc) {
  const int blk = blockIdx.x;
  const int c   = blk & (NCHUNK - 1);
  const int h   = blk >> 5;
  const int l0  = c * LCHUNK;
  const int t   = threadIdx.x;
  const int wave = t >> 6, lane = t & 63;
  const int ml = lane & 15, g4 = lane >> 4;
  const float Ah = -expf(A_log[h]);

  __shared__ float cum[LCHUNK];
  __shared__ float carry;
  __shared__ ushort Xt[2][LCHUNK * 40];
  __shared__ ushort Bt[2][D_STATE * 40];

  {
    float v = 0.f;
    if (t < LCHUNK) {
      float xv = dtb[(size_t)(l0 + t) * NHEADS + h] + dt_bias[h];
      float sp = (xv > 20.f) ? xv : log1pf(expf(xv));
      v = sp * Ah;
    }
    cum_scan(cum, v, t, &carry);
  }
  const float cend = cum[LCHUNK - 1];

  f32x4 acc[2][4];
#pragma unroll
  for (int i = 0; i < 2; ++i)
#pragma unroll
    for (int j = 0; j < 4; ++j) acc[i][j] = (f32x4){0.f, 0.f, 0.f, 0.f};
  const int p0 = wave * 32;

  for (int slab = 0; slab < 4; ++slab) {
    __syncthreads();
    for (int i = 0; i < 4; ++i) {
      int q = t + i * 256;
      int s = q >> 5, p4 = (q & 31) * 4;
      int l = l0 + slab * 32 + s;
      float xv[4];
      conv4b(zx, cw, cb, l, 2048 + h * HEADDIM + p4, xv);
#pragma unroll
      for (int j = 0; j < 4; ++j) {
        ushort hh = f2bf(xv[j]);
        Xt[0][(p4 + j) * 40 + s] = hh;
        Xt[1][(p4 + j) * 40 + s] = f2bf(xv[j] - bf2f(hh));
      }
    }
    for (int i = 0; i < 2; ++i) {
      int q = t + i * 256;
      int s = q >> 4, n4 = (q & 15) * 4;
      int l = l0 + slab * 32 + s;
      float wd = __expf(cend - cum[slab * 32 + s]);
      float bv[4];
      conv4b(zx, cw, cb, l, 4096 + n4, bv);
#pragma unroll
      for (int j = 0; j < 4; ++j) {
        float val = bv[j] * wd;
        ushort hh = f2bf(val);
        Bt[0][(n4 + j) * 40 + s] = hh;
        Bt[1][(n4 + j) * 40 + s] = f2bf(val - bf2f(hh));
      }
    }
    __syncthreads();

    short8 xa_h[2], xa_l[2];
#pragma unroll
    for (int pi = 0; pi < 2; ++pi) {
      int off = (p0 + pi * 16 + ml) * 40 + g4 * 8;
      xa_h[pi] = *(const short8*)&Xt[0][off];
      xa_l[pi] = *(const short8*)&Xt[1][off];
    }
#pragma unroll
    for (int ni = 0; ni < 4; ++ni) {
      int off = (ni * 16 + ml) * 40 + g4 * 8;
      short8 bh = *(const short8*)&Bt[0][off];
      short8 bl = *(const short8*)&Bt[1][off];
#pragma unroll
      for (int pi = 0; pi < 2; ++pi) {
        acc[pi][ni] = __builtin_amdgcn_mfma_f32_16x16x32_bf16(xa_h[pi], bh, acc[pi][ni], 0, 0, 0);
        acc[pi][ni] = __builtin_amdgcn_mfma_f32_16x16x32_bf16(xa_h[pi], bl, acc[pi][ni], 0, 0, 0);
        acc[pi][ni] = __builtin_amdgcn_mfma_f32_16x16x32_bf16(xa_l[pi], bh, acc[pi][ni], 0, 0, 0);
      }
    }
  }

  float* S = Sc + (size_t)blk * (HEADDIM * D_STATE);
#pragma unroll
  for (int pi = 0; pi < 2; ++pi)
#pragma unroll
    for (int ni = 0; ni < 4; ++ni) {
      int n = ni * 16 + ml;
#pragma unroll
      for (int r = 0; r < 4; ++r) {
        int p = p0 + pi * 16 + g4 * 4 + r;
        S[(size_t)p * D_STATE + n] = acc[pi][ni][r];
      }
    }
  if (t == 0) Pc[blk] = __expf(cend);
}

// ---------------- pass B: exclusive prefix over chunks ----------------
__global__ void scan_passB(float* __restrict__ Sc, const float* __restrict__ Pc) {
  const int h = blockIdx.x;
  const int e = blockIdx.y * 512 + threadIdx.x;
  const size_t hb = (size_t)h * NCHUNK;
  float st = 0.f;
  for (int c = 0; c < NCHUNK; ++c) {
    size_t idx = (hb + c) * (HEADDIM * D_STATE) + e;
    float P = Pc[hb + c];
    float v = Sc[idx];
    Sc[idx] = st;
    st = fmaf(P, st, v);
  }
}

// ---------------- pass C: intra-chunk attention + inter-chunk term -> y ----------
__launch_bounds__(256, 2)
__global__ void passC_ssd(const ushort* __restrict__ zx,
                          const float* __restrict__ dtb,
                          const float* __restrict__ cw, const float* __restrict__ cb,
                          const float* __restrict__ dt_bias,
                          const float* __restrict__ A_log,
                          const float* __restrict__ Dp,
                          const float* __restrict__ Sc,
                          float* __restrict__ ybuf) {
  const int blk = blockIdx.x;
  const int c   = blk & (NCHUNK - 1);
  const int h   = blk >> 5;
  const int l0  = c * LCHUNK;
  const int t   = threadIdx.x;
  const int wave = t >> 6, lane = t & 63;
  const int ml = lane & 15, g4 = lane >> 4;
  const float Ah = -expf(A_log[h]);
  const float Dh = Dp[h];

  __shared__ float cum[LCHUNK];
  __shared__ float carry;
  __shared__ ushort Csl[2][2][LCHUNK * 32];
  __shared__ ushort Bsl[2][2][32 * 32];
  __shared__ ushort Msl[2][LCHUNK * 32];
  __shared__ ushort Xt[2][LCHUNK * 40];

  {
    float v = 0.f;
    if (t < LCHUNK) {
      float xv = dtb[(size_t)(l0 + t) * NHEADS + h] + dt_bias[h];
      float sp = (xv > 20.f) ? xv : log1pf(expf(xv));
      v = sp * Ah;
    }
    cum_scan(cum, v, t, &carry);
  }

  // stage C (resident), inline conv: cols 4160..4224
  {
    int row = t >> 1, half = t & 1;
    int l = l0 + row;
    int colbase = 4160 + half * 32;
#pragma unroll
    for (int j0 = 0; j0 < 32; j0 += 4) {
      float cv[4];
      conv4b(zx, cw, cb, l, colbase + j0, cv);
      ushort h0 = f2bf(cv[0]), h1 = f2bf(cv[1]), h2 = f2bf(cv[2]), h3 = f2bf(cv[3]);
      *(ushort4*)&Csl[half][0][row * 32 + j0] = make_ushort4(h0, h1, h2, h3);
      *(ushort4*)&Csl[half][1][row * 32 + j0] =
          make_ushort4(f2bf(cv[0] - bf2f(h0)), f2bf(cv[1] - bf2f(h1)),
                       f2bf(cv[2] - bf2f(h2)), f2bf(cv[3] - bf2f(h3)));
    }
  }

  f32x4 accY[2][8];
#pragma unroll
  for (int i = 0; i < 2; ++i)
#pragma unroll
    for (int j = 0; j < 8; ++j) accY[i][j] = (f32x4){0.f, 0.f, 0.f, 0.f};
  const int t0 = wave * 32;

  // ---- intra-chunk: 4 s-slabs ----
  for (int slab = 0; slab < 4; ++slab) {
    __syncthreads();
    for (int i = 0; i < 2; ++i) {
      int q = t + i * 256;
      int s = q >> 4, c4 = (q & 15) * 4;
      int l = l0 + slab * 32 + s;
      float bv[4];
      conv4b(zx, cw, cb, l, 4096 + c4, bv);
      int ks = c4 >> 5, jj = c4 & 31;
      ushort h0 = f2bf(bv[0]), h1 = f2bf(bv[1]), h2 = f2bf(bv[2]), h3 = f2bf(bv[3]);
      *(ushort4*)&Bsl[ks][0][s * 32 + jj] = make_ushort4(h0, h1, h2, h3);
      *(ushort4*)&Bsl[ks][1][s * 32 + jj] =
          make_ushort4(f2bf(bv[0] - bf2f(h0)), f2bf(bv[1] - bf2f(h1)),
                       f2bf(bv[2] - bf2f(h2)), f2bf(bv[3] - bf2f(h3)));
    }
    for (int i = 0; i < 4; ++i) {
      int q = t + i * 256;
      int s = q >> 5, p4 = (q & 31) * 4;
      int l = l0 + slab * 32 + s;
      float xv[4];
      conv4b(zx, cw, cb, l, 2048 + h * HEADDIM + p4, xv);
#pragma unroll
      for (int j = 0; j < 4; ++j) {
        ushort hh = f2bf(xv[j]);
        Xt[0][(p4 + j) * 40 + s] = hh;
        Xt[1][(p4 + j) * 40 + s] = f2bf(xv[j] - bf2f(hh));
      }
    }
    __syncthreads();

    // phase 1: G = C . B^T
    f32x4 g[2][2];
#pragma unroll
    for (int i = 0; i < 2; ++i)
#pragma unroll
      for (int j = 0; j < 2; ++j) g[i][j] = (f32x4){0.f, 0.f, 0.f, 0.f};
#pragma unroll
    for (int ks = 0; ks < 2; ++ks) {
      short8 ca_h[2], ca_l[2];
#pragma unroll
      for (int ti = 0; ti < 2; ++ti) {
        int off = (t0 + ti * 16 + ml) * 32 + g4 * 8;
        ca_h[ti] = *(const short8*)&Csl[ks][0][off];
        ca_l[ti] = *(const short8*)&Csl[ks][1][off];
      }
#pragma unroll
      for (int si = 0; si < 2; ++si) {
        int off = (si * 16 + ml) * 32 + g4 * 8;
        short8 bh = *(const short8*)&Bsl[ks][0][off];
        short8 bl = *(const short8*)&Bsl[ks][1][off];
#pragma unroll
        for (int ti = 0; ti < 2; ++ti) {
          g[ti][si] = __builtin_amdgcn_mfma_f32_16x16x32_bf16(ca_h[ti], bh, g[ti][si], 0, 0, 0);
          g[ti][si] = __builtin_amdgcn_mfma_f32_16x16x32_bf16(ca_h[ti], bl, g[ti][si], 0, 0, 0);
          g[ti][si] = __builtin_amdgcn_mfma_f32_16x16x32_bf16(ca_l[ti], bh, g[ti][si], 0, 0, 0);
        }
      }
    }
    // mask + decay (+ D diagonal) -> Msl
#pragma unroll
    for (int ti = 0; ti < 2; ++ti)
#pragma unroll
      for (int si = 0; si < 2; ++si) {
        int sl = si * 16 + ml;
        int sg = slab * 32 + sl;
#pragma unroll
        for (int r = 0; r < 4; ++r) {
          int tg = t0 + ti * 16 + g4 * 4 + r;
          float coeff = (sg <= tg) ? __expf(cum[tg] - cum[sg]) : 0.f;
          float val = g[ti][si][r] * coeff + ((sg == tg) ? Dh : 0.f);
          ushort hh = f2bf(val);
          Msl[0][tg * 32 + sl] = hh;
          Msl[1][tg * 32 + sl] = f2bf(val - bf2f(hh));
        }
      }
    __syncthreads();
    // phase 2: Y += M . X^T
    {
      short8 ma_h[2], ma_l[2];
#pragma unroll
      for (int ti = 0; ti < 2; ++ti) {
        int off = (t0 + ti * 16 + ml) * 32 + g4 * 8;
        ma_h[ti] = *(const short8*)&Msl[0][off];
        ma_l[ti] = *(const short8*)&Msl[1][off];
      }
#pragma unroll
      for (int pi = 0; pi < 8; ++pi) {
        int off = (pi * 16 + ml) * 40 + g4 * 8;
        short8 xh = *(const short8*)&Xt[0][off];
        short8 xl = *(const short8*)&Xt[1][off];
#pragma unroll
        for (int ti = 0; ti < 2; ++ti) {
          accY[ti][pi] = __builtin_amdgcn_mfma_f32_16x16x32_bf16(ma_h[ti], xh, accY[ti][pi], 0, 0, 0);
          accY[ti][pi] = __builtin_amdgcn_mfma_f32_16x16x32_bf16(ma_h[ti], xl, accY[ti][pi], 0, 0, 0);
          accY[ti][pi] = __builtin_amdgcn_mfma_f32_16x16x32_bf16(ma_l[ti], xh, accY[ti][pi], 0, 0, 0);
        }
      }
    }
  }

  // ---- inter-chunk: Y += diag(exp(cum)) C . S_init ----
  const float* S = Sc + (size_t)blk * (HEADDIM * D_STATE);
  for (int ns = 0; ns < 2; ++ns) {
    __syncthreads();
    for (int i = 0; i < 4; ++i) {
      int q = t + i * 256;
      int p = q >> 3, j4 = (q & 7) * 4;
      float4 v = *(const float4*)(S + (size_t)p * D_STATE + ns * 32 + j4);
      float vv[4] = {v.x, v.y, v.z, v.w};
      ushort hh0 = f2bf(vv[0]), hh1 = f2bf(vv[1]), hh2 = f2bf(vv[2]), hh3 = f2bf(vv[3]);
      *(ushort4*)&Xt[0][p * 40 + j4] = make_ushort4(hh0, hh1, hh2, hh3);
      *(ushort4*)&Xt[1][p * 40 + j4] =
          make_ushort4(f2bf(vv[0] - bf2f(hh0)), f2bf(vv[1] - bf2f(hh1)),
                       f2bf(vv[2] - bf2f(hh2)), f2bf(vv[3] - bf2f(hh3)));
    }
    {
      int row = t >> 1, j0 = (t & 1) * 16;
      float e = __expf(cum[row]);
#pragma unroll
      for (int j = 0; j < 16; ++j) {
        int idx = row * 32 + j0 + j;
        float cv = bf2f(Csl[ns][0][idx]) + bf2f(Csl[ns][1][idx]);
        float val = cv * e;
        ushort hh = f2bf(val);
        Msl[0][idx] = hh;
        Msl[1][idx] = f2bf(val - bf2f(hh));
      }
    }
    __syncthreads();
    {
      short8 ma_h[2], ma_l[2];
#pragma unroll
      for (int ti = 0; ti < 2; ++ti) {
        int off = (t0 + ti * 16 + ml) * 32 + g4 * 8;
        ma_h[ti] = *(const short8*)&Msl[0][off];
        ma_l[ti] = *(const short8*)&Msl[1][off];
      }
#pragma unroll
      for (int pi = 0; pi < 8; ++pi) {
        int off = (pi * 16 + ml) * 40 + g4 * 8;
        short8 xh = *(const short8*)&Xt[0][off];
        short8 xl = *(const short8*)&Xt[1][off];
#pragma unroll
        for (int ti = 0; ti < 2; ++ti) {
          accY[ti][pi] = __builtin_amdgcn_mfma_f32_16x16x32_bf16(ma_h[ti], xh, accY[ti][pi], 0, 0, 0);
          accY[ti][pi] = __builtin_amdgcn_mfma_f32_16x16x32_bf16(ma_h[ti], xl, accY[ti][pi], 0, 0, 0);
          accY[ti][pi] = __builtin_amdgcn_mfma_f32_16x16x32_bf16(ma_l[ti], xh, accY[ti][pi], 0, 0, 0);
        }
      }
    }
  }

  // ---- epilogue: y = accY ----
#pragma unroll
  for (int ti = 0; ti < 2; ++ti)
#pragma unroll
    for (int pi = 0; pi < 8; ++pi) {
      int p = pi * 16 + ml;
#pragma unroll
      for (int r = 0; r < 4; ++r) {
        int l = l0 + t0 + ti * 16 + g4 * 4 + r;
        ybuf[(size_t)l * D_INNER + h * HEADDIM + p] = accY[ti][pi][r];
      }
    }
}

// ------- RMSNorm + sigmoid(z) gate (z bf16 in zxbc), emits gated y bf16 -------
__launch_bounds__(256)
__global__ void rmsnorm_gate_split(const float* __restrict__ ybuf,
                                   const ushort* __restrict__ zx,
                                   const float* __restrict__ rms_w,
                                   ushort* __restrict__ yh) {
  const int row = blockIdx.x;
  const int t   = threadIdx.x;
  const float* y  = ybuf + (size_t)row * D_INNER;
  const ushort* z = zx   + (size_t)row * ZX_LD;      // z cols [0,2048)

  float4 a  = *(const float4*)(y + t * 8);
  float4 bq = *(const float4*)(y + t * 8 + 4);
  float ss = a.x * a.x + a.y * a.y + a.z * a.z + a.w * a.w +
             bq.x * bq.x + bq.y * bq.y + bq.z * bq.z + bq.w * bq.w;
#pragma unroll
  for (int off = 32; off > 0; off >>= 1) ss += __shfl_down(ss, off);
  __shared__ float red[4];
  if ((t & 63) == 0) red[t >> 6] = ss;
  __syncthreads();
  float tot = red[0] + red[1] + red[2] + red[3];
  float scale = rsqrtf(tot * (1.f / (float)D_INNER) + RMS_EPS);

  float vy[8] = {a.x, a.y, a.z, a.w, bq.x, bq.y, bq.z, bq.w};
  ushort4 zv0 = *(const ushort4*)(z + t * 8);
  ushort4 zv1 = *(const ushort4*)(z + t * 8 + 4);
  ushort zz[8] = {zv0.x, zv0.y, zv0.z, zv0.w, zv1.x, zv1.y, zv1.z, zv1.w};
  ushort hh[8];
#pragma unroll
  for (int jj = 0; jj < 8; ++jj) {
    int col = t * 8 + jj;
    float g = 1.f / (1.f + __expf(-bf2f(zz[jj])));
    float v = vy[jj] * scale * rms_w[col] * g;
    hh[jj] = f2bf(v);
  }
  size_t o = (size_t)row * D_INNER + t * 8;
  *(ushort4*)(yh + o)     = make_ushort4(hh[0], hh[1], hh[2], hh[3]);
  *(ushort4*)(yh + o + 4) = make_ushort4(hh[4], hh[5], hh[6], hh[7]);
}

// ---------------- launch ----------------
// ws layout identical to R9/R10 (129.8 MB, known-good).
extern "C" void kernel_launch(void* const* d_in, const int* in_sizes, int n_in,
                              void* d_out, int out_size, void* d_ws, size_t ws_size,
                              hipStream_t stream) {
  const float* u         = (const float*)d_in[0];
  const float* in_proj_w = (const float*)d_in[1];
  const float* conv_w    = (const float*)d_in[2];
  const float* conv_b    = (const float*)d_in[3];
  const float* dt_bias   = (const float*)d_in[4];
  const float* A_log     = (const float*)d_in[5];
  const float* Dp        = (const float*)d_in[6];
  const float* rms_w     = (const float*)d_in[7];
  const float* out_w     = (const float*)d_in[8];
  float* out = (float*)d_out;

  float* ws    = (float*)d_ws;
  ushort* zxbc = (ushort*)ws;                                  // [4096, 4224] bf16
  float* dtb   = ws   + (size_t)SEQLEN * ZX_LD / 2;            // [4096, 16]
  float* dtp   = dtb  + (size_t)SEQLEN * NHEADS;               // [8, 4096, 16]
  float* ybuf  = dtp  + (size_t)8 * SEQLEN * NHEADS;           // [4096, 2048]
  float* Pc    = ybuf + (size_t)SEQLEN * D_INNER;              // [512]
  float* Sc    = Pc   + 512;                                   // [512, 8192]
  ushort* uh   = (ushort*)(Sc + (size_t)NHEADS * NCHUNK * HEADDIM * D_STATE);
  ushort* ul   = uh  + (size_t)SEQLEN * D_MODEL;
  ushort* w1h  = ul  + (size_t)SEQLEN * D_MODEL;
  ushort* w1l  = w1h + (size_t)D_IN_PROJ * D_MODEL;
  ushort* w2h  = w1l + (size_t)D_IN_PROJ * D_MODEL;
  ushort* w2l  = w2h + (size_t)D_MODEL * D_INNER;
  ushort* yh   = (ushort*)Sc;                                  // overlay Sc (dead)
  float* Opart = ybuf;                                         // overlay ybuf (dead)

  // weight splits (once per call)
  {
    int n4 = D_IN_PROJ * D_MODEL / 4;
    cvt_split<<<(n4 + 255) / 256, 256, 0, stream>>>(in_proj_w, w1h, w1l, n4);
    int m4 = D_MODEL * D_INNER / 4;
    cvt_split<<<(m4 + 255) / 256, 256, 0, stream>>>(out_w, w2h, w2l, m4);
  }

  for (int b = 0; b < BATCH; ++b) {
    const float* u_b  = u   + (size_t)b * SEQLEN * D_MODEL;
    float*      out_b = out + (size_t)b * SEQLEN * D_MODEL;

    // 0) split u_b -> bf16 planes
    {
      int n4 = SEQLEN * D_MODEL / 4;
      cvt_split<<<(n4 + 255) / 256, 256, 0, stream>>>(u_b, uh, ul, n4);
    }

    // 1) merged z|x|B|C GEMM: z cols (<2048) 1-term, x|B|C 2-term, bf16 out.
    //    BK=64 (16 K-iters: half the barrier-drain tax) + XOR-swizzled staging
    //    (fragment b128 reads spread across all 32 banks). grid.x padded 33->40
    //    for stable col-tile -> XCD (%8) L2 residency (R10: FETCH 228->46MB).
    {
      dim3 g(40, SEQLEN / 128, 1);
      gemm_bf16p<128, 64, false, true><<<g, 256, 0, stream>>>(uh, uh, w1h, w1l,
                                                          (float*)zxbc, ZX_LD, SEQLEN,
                                                          ZX_LD, D_MODEL, D_MODEL,
                                                          D_INNER);
    }
    // 1b) dt GEMM (3-term, split-K=8): N=16, near-fp32 (dt feeds exponentials)
    {
      const ushort* bh = w1h + (size_t)ZX_LD * D_MODEL;
      const ushort* bl = w1l + (size_t)ZX_LD * D_MODEL;
      dim3 g(1, SEQLEN / 128, 8);
      gemm_bf16p<128, 32, true, false><<<g, 256, 0, stream>>>(uh, ul, bh, bl,
                                                          dtp, NHEADS, SEQLEN, NHEADS,
                                                          D_MODEL, D_MODEL / 8, 0);
      add_dt<<<(SEQLEN * NHEADS / 4 + 255) / 256, 256, 0, stream>>>(dtp, dtb);
    }

    // 2-4) SSD chunked scan on MFMA (conv+SiLU fused; D via mask diagonal)
    passA_ssd<<<NHEADS * NCHUNK, 256, 0, stream>>>(zxbc, dtb, conv_w, conv_b,
                                                   dt_bias, A_log, Sc, Pc);
    scan_passB<<<dim3(NHEADS, (HEADDIM * D_STATE) / 512), 512, 0, stream>>>(Sc, Pc);
    passC_ssd<<<NHEADS * NCHUNK, 256, 0, stream>>>(zxbc, dtb, conv_w, conv_b,
                                                   dt_bias, A_log, Dp, Sc, ybuf);

    // 5) RMSNorm + gate -> y bf16 (overlays Sc, dead now)
    rmsnorm_gate_split<<<SEQLEN, 256, 0, stream>>>(ybuf, zxbc, rms_w, yh);

    // 6) out GEMM, split-K=2, 2-term, BK=64 -> partials over ybuf (dead)
    {
      dim3 g(D_MODEL / 128, SEQLEN / 128, 2);
      gemm_bf16p<128, 64, false, false><<<g, 256, 0, stream>>>(yh, yh, w2h, w2l,
                                                           Opart, D_MODEL, SEQLEN, D_MODEL,
                                                           D_INNER, D_INNER / 2, 0);
    }
    // 7) combine partials -> out_b
    add_out<<<(SEQLEN * D_MODEL / 4 + 255) / 256, 256, 0, stream>>>(Opart, out_b,
                                                                    SEQLEN * D_MODEL / 4);
  }
}